// Round 3
// baseline (438.205 us; speedup 1.0000x reference)
//
#include <hip/hip_runtime.h>
#include <math.h>
#include <stdint.h>

constexpr int kB = 4;
constexpr int kS = 2048;
constexpr int kD = 1024;
constexpr int kH = 16;
constexpr int kHD = 64;

typedef __bf16 bf16;
typedef __attribute__((ext_vector_type(4))) __bf16 bf16x4;
typedef __attribute__((ext_vector_type(8))) __bf16 bf16x8;
typedef __attribute__((ext_vector_type(4))) float f32x4;

__device__ __forceinline__ f32x4 mfma16x16x32(bf16x8 a, bf16x8 b, f32x4 c) {
    return __builtin_amdgcn_mfma_f32_16x16x32_bf16(a, b, c, 0, 0, 0);
}

#if __has_builtin(__builtin_amdgcn_exp2f)
#define EXP2F(x) __builtin_amdgcn_exp2f(x)
#else
#define EXP2F(x) exp2f(x)
#endif

// async 16B global->LDS. lds base must be wave-uniform; HW adds lane*16.
__device__ __forceinline__ void load_lds16(const bf16* g, bf16* lds) {
    __builtin_amdgcn_global_load_lds(
        (const __attribute__((address_space(1))) void*)g,
        (__attribute__((address_space(3))) void*)lds, 16, 0, 0);
}

// ---------------------------------------------------------------------------
// prep_x: fp32 -> bf16 convert of x (8192x1024).
// ---------------------------------------------------------------------------
__global__ __launch_bounds__(256) void prep_x(const float* __restrict__ x,
                                              bf16* __restrict__ xb) {
    size_t i = ((size_t)blockIdx.x * 256 + threadIdx.x) * 8;
    float4 f0 = *(const float4*)(x + i);
    float4 f1 = *(const float4*)(x + i + 4);
    bf16x8 v;
    v[0] = (bf16)f0.x; v[1] = (bf16)f0.y; v[2] = (bf16)f0.z; v[3] = (bf16)f0.w;
    v[4] = (bf16)f1.x; v[5] = (bf16)f1.y; v[6] = (bf16)f1.z; v[7] = (bf16)f1.w;
    *(bf16x8*)(xb + i) = v;
}

// ---------------------------------------------------------------------------
// prep_w: Wt[z*1024 + n][k] = W_z[k][n] * scale_z (bf16, transposed)
// z=0 Wq scaled by 0.125*log2(e) (exp2-domain softmax), 1=Wk, 2=Wv, 3=Wo.
// ---------------------------------------------------------------------------
__global__ __launch_bounds__(256) void prep_w(const float* __restrict__ Wq,
                                              const float* __restrict__ Wk,
                                              const float* __restrict__ Wv,
                                              const float* __restrict__ Wo,
                                              bf16* __restrict__ Wt) {
    __shared__ bf16 t[64 * 72];
    const int z = blockIdx.z;
    const float* W = (z == 0) ? Wq : (z == 1) ? Wk : (z == 2) ? Wv : Wo;
    const float scale = (z == 0) ? 0.18033688011112042f : 1.0f;
    const int k0 = blockIdx.x * 64, n0 = blockIdx.y * 64;
    const int tid = threadIdx.x;
    for (int p = 0; p < 16; ++p) {
        int idx = tid + p * 256;
        int r = idx >> 6, c = idx & 63;
        t[r * 72 + c] = (bf16)(W[(size_t)(k0 + r) * kD + n0 + c] * scale);
    }
    __syncthreads();
    for (int p = 0; p < 16; ++p) {
        int idx = tid + p * 256;
        int r = idx >> 6, c = idx & 63;
        Wt[(size_t)(z * 1024 + n0 + r) * kD + k0 + c] = t[c * 72 + r];
    }
}

// ---------------------------------------------------------------------------
// qkv_gemm: m97 structure. 128x128 tile, BK=64, unpadded LDS, staged via
// global_load_lds width=16.  4 waves 2x2, each 64x64.
// Q,K -> [B,H,S,HD]; V -> transposed [B,H,HD,S].
// ---------------------------------------------------------------------------
__global__ __launch_bounds__(256) void qkv_gemm(
    const bf16* __restrict__ xb, const bf16* __restrict__ Wt,
    bf16* __restrict__ qo, bf16* __restrict__ ko, bf16* __restrict__ vto)
{
    __shared__ bf16 As[128 * 64];
    __shared__ bf16 Bs[128 * 64];

    const int tid  = threadIdx.x;
    const int wave = tid >> 6;
    const int lane = tid & 63;
    const int quad = lane >> 4;
    const int lr   = lane & 15;
    const int wm   = wave >> 1, wn = wave & 1;

    const int m0 = blockIdx.x * 128;
    const int n0 = blockIdx.y * 128;

    const int sr = tid >> 3, sc = tid & 7;   // staging row/16B-block (per p: +32 rows)

    f32x4 acc[4][4];
#pragma unroll
    for (int i = 0; i < 4; ++i)
#pragma unroll
        for (int nt = 0; nt < 4; ++nt) acc[i][nt] = f32x4{0.f, 0.f, 0.f, 0.f};

    for (int k0 = 0; k0 < kD; k0 += 64) {
        __syncthreads();
#pragma unroll
        for (int p = 0; p < 4; ++p) {
            int r = p * 32 + sr;
            load_lds16(&xb[(size_t)(m0 + r) * kD + k0 + sc * 8],
                       &As[(p * 256 + wave * 64) * 8]);
            load_lds16(&Wt[(size_t)(n0 + r) * kD + k0 + sc * 8],
                       &Bs[(p * 256 + wave * 64) * 8]);
        }
        __syncthreads();
#pragma unroll
        for (int kk = 0; kk < 2; ++kk) {
            bf16x8 a[4], b[4];
#pragma unroll
            for (int i = 0; i < 4; ++i)
                a[i] = *(const bf16x8*)&As[(wm * 64 + i * 16 + lr) * 64 + kk * 32 + quad * 8];
#pragma unroll
            for (int nt = 0; nt < 4; ++nt)
                b[nt] = *(const bf16x8*)&Bs[(wn * 64 + nt * 16 + lr) * 64 + kk * 32 + quad * 8];
#pragma unroll
            for (int i = 0; i < 4; ++i)
#pragma unroll
                for (int nt = 0; nt < 4; ++nt)
                    acc[i][nt] = mfma16x16x32(a[i], b[nt], acc[i][nt]);
        }
    }

    const int w_idx = n0 >> 10;               // 0=Q,1=K,2=V (uniform per block)
    if (w_idx < 2) {
        bf16* dst = (w_idx == 0) ? qo : ko;   // [B,H,S,HD]
#pragma unroll
        for (int i = 0; i < 4; ++i)
#pragma unroll
            for (int nt = 0; nt < 4; ++nt) {
                int n   = n0 + wn * 64 + nt * 16 + lr;
                int col = n & 1023, h = col >> 6, hd = col & 63;
#pragma unroll
                for (int j = 0; j < 4; ++j) {
                    int m = m0 + wm * 64 + i * 16 + quad * 4 + j;
                    int b = m >> 11, s = m & 2047;
                    dst[((size_t)(b * kH + h) * kS + s) * kHD + hd] = (bf16)acc[i][nt][j];
                }
            }
    } else {
        // V transposed: [B,H,HD,S]; j walks s -> bf16x4 stores
#pragma unroll
        for (int i = 0; i < 4; ++i)
#pragma unroll
            for (int nt = 0; nt < 4; ++nt) {
                int n   = n0 + wn * 64 + nt * 16 + lr;
                int col = n & 1023, h = col >> 6, hd = col & 63;
                int mb  = m0 + wm * 64 + i * 16 + quad * 4;
                int b = mb >> 11, s = mb & 2047;
                bf16x4 pk;
#pragma unroll
                for (int j = 0; j < 4; ++j) pk[j] = (bf16)acc[i][nt][j];
                *(bf16x4*)&vto[((size_t)(b * kH + h) * kHD + hd) * kS + s] = pk;
            }
    }
}

// ---------------------------------------------------------------------------
// attn v6: causal attention, exp2-domain, unnormalized accumulation.
// Occupancy fix on top of v5: 4-wave (256-thread) blocks, 16 q-rows/wave.
// 1024 blocks x 4 waves = 4096 waves = sustained 4 waves/SIMD (v5 was 2).
// All 4 waves read the SAME K/V tile (same addresses -> L1/L2 hits; FETCH
// stays ~29MB, unlike round-1's disjoint-tile split).
// Block (bh, p) processes q-blocks 31-p then p: 33 tiles for every block.
// Swapped QK^T (mfma(K,Q)); P through per-wave LDS (16x72, double-buffered);
// no barriers anywhere in the loop.  __launch_bounds__(256,4) caps VGPR<=128.
// ---------------------------------------------------------------------------
__global__ __launch_bounds__(256, 4) void attn(
    const bf16* __restrict__ q, const bf16* __restrict__ k,
    const bf16* __restrict__ vt, bf16* __restrict__ ctx)
{
    __shared__ bf16 Pl[4][2][16 * 72];   // [wave][buf][qrow*72+key]

    const int tid  = threadIdx.x;
    const int wave = tid >> 6;
    const int lane = tid & 63;
    const int quad = lane >> 4;
    const int lr   = lane & 15;

    const int bh = blockIdx.x;
    const int p  = blockIdx.y;           // 0..15

    const bf16* qb_p = q  + (size_t)bh * kS * kHD;
    const bf16* kb_p = k  + (size_t)bh * kS * kHD;
    const bf16* vt_p = vt + (size_t)bh * kHD * kS; // [hd][s]

    bf16x8 ones;
#pragma unroll
    for (int i = 0; i < 8; ++i) ones[i] = (bf16)1.0f;

    // per-lane base element offsets
    const size_t koff = (size_t)lr * kHD + quad * 8;   // + kt*64*64 + nt*1024 + kk*32
    const size_t voff = (size_t)lr * kS + quad * 8;    // + nt*16*2048 + kt*64 + kk*32
    bf16* Pw = &Pl[wave][0][0];

    const int b = bh >> 4;
    const int h = bh & 15;

#pragma unroll 1
    for (int gi = 0; gi < 2; ++gi) {
        const int qb   = gi ? p : (31 - p);   // q-block 0..31 (heavy first)
        const int T    = qb + 1;              // k-tiles
        const int base = qb * 64 + wave * 16; // first q-row of this wave

        bf16x8 aq[2];
#pragma unroll
        for (int kk = 0; kk < 2; ++kk)
            aq[kk] = *(const bf16x8*)&qb_p[(size_t)(base + lr) * kHD + kk * 32 + quad * 8];

        f32x4 o[4];
        f32x4 lacc = f32x4{0.f, 0.f, 0.f, 0.f};
#pragma unroll
        for (int nt = 0; nt < 4; ++nt) o[nt] = f32x4{0.f, 0.f, 0.f, 0.f};

#pragma unroll 1
        for (int kt = 0; kt < T; ++kt) {
            const int k0 = kt * 64;
            bf16* Pb = Pw + (kt & 1) * (16 * 72);

            // issue K and V loads together; QK waits on K, PV on V (arrives
            // well before use).  4 waves/SIMD cover the L2-hit latency.
            bf16x8 kf[4][2], vf[4][2];
#pragma unroll
            for (int nt = 0; nt < 4; ++nt) {
                const bf16* kr = kb_p + koff + (size_t)k0 * kHD + nt * 1024;
                kf[nt][0] = *(const bf16x8*)kr;
                kf[nt][1] = *(const bf16x8*)(kr + 32);
                const bf16* vr = vt_p + voff + (size_t)nt * 16 * kS + k0;
                vf[nt][0] = *(const bf16x8*)vr;
                vf[nt][1] = *(const bf16x8*)(vr + 32);
            }

            // swapped QK^T: lane holds q-row = base+lr,
            // keys k0 + nt*16 + quad*4 + j (4 consecutive keys per reg)
            f32x4 sg[4];
#pragma unroll
            for (int nt = 0; nt < 4; ++nt) {
                sg[nt] = mfma16x16x32(kf[nt][0], aq[0], f32x4{0.f, 0.f, 0.f, 0.f});
                sg[nt] = mfma16x16x32(kf[nt][1], aq[1], sg[nt]);
            }

            if (kt == T - 1) {
                const int qg = base + lr;
#pragma unroll
                for (int nt = 0; nt < 4; ++nt) {
                    bf16x4 pk;
#pragma unroll
                    for (int j = 0; j < 4; ++j) {
                        float s = sg[nt][j];
                        s = (k0 + nt * 16 + quad * 4 + j > qg) ? -3.0e38f : s;
                        pk[j] = (bf16)EXP2F(s);
                    }
                    *(bf16x4*)&Pb[lr * 72 + nt * 16 + quad * 4] = pk;
                }
            } else {
#pragma unroll
                for (int nt = 0; nt < 4; ++nt) {
                    bf16x4 pk;
#pragma unroll
                    for (int j = 0; j < 4; ++j) pk[j] = (bf16)EXP2F(sg[nt][j]);
                    *(bf16x4*)&Pb[lr * 72 + nt * 16 + quad * 4] = pk;
                }
            }

            // O += P @ V ; l += P @ ones   (P read back in A-operand layout)
#pragma unroll
            for (int kk = 0; kk < 2; ++kk) {
                bf16x8 pa = *(const bf16x8*)&Pb[lr * 72 + kk * 32 + quad * 8];
                lacc = mfma16x16x32(pa, ones, lacc);
#pragma unroll
                for (int nt = 0; nt < 4; ++nt)
                    o[nt] = mfma16x16x32(pa, vf[nt][kk], o[nt]);
            }
        }

        // ctx [B,S,D] bf16, column h*64+hd; rows base+quad*4+j
        float inv[4];
#pragma unroll
        for (int j = 0; j < 4; ++j) inv[j] = 1.0f / lacc[j];
#pragma unroll
        for (int nt = 0; nt < 4; ++nt) {
            int hd = nt * 16 + lr;
#pragma unroll
            for (int j = 0; j < 4; ++j) {
                int qg = base + quad * 4 + j;
                ctx[((size_t)(b * kS + qg)) * kD + h * kHD + hd] = (bf16)(o[nt][j] * inv[j]);
            }
        }
    }
}

// ---------------------------------------------------------------------------
// out_gemm: out = ctx @ Wo + bo (fp32).  Same m97 structure.
// ---------------------------------------------------------------------------
__global__ __launch_bounds__(256) void out_gemm(
    const bf16* __restrict__ ctxb, const bf16* __restrict__ Wto,
    const float* __restrict__ bo, float* __restrict__ out)
{
    __shared__ bf16 As[128 * 64];
    __shared__ bf16 Bs[128 * 64];

    const int tid  = threadIdx.x;
    const int wave = tid >> 6;
    const int lane = tid & 63;
    const int quad = lane >> 4;
    const int lr   = lane & 15;
    const int wm   = wave >> 1, wn = wave & 1;

    const int m0 = blockIdx.x * 128;
    const int n0 = blockIdx.y * 128;

    const int sr = tid >> 3, sc = tid & 7;

    f32x4 acc[4][4];
#pragma unroll
    for (int i = 0; i < 4; ++i)
#pragma unroll
        for (int nt = 0; nt < 4; ++nt) acc[i][nt] = f32x4{0.f, 0.f, 0.f, 0.f};

    for (int k0 = 0; k0 < kD; k0 += 64) {
        __syncthreads();
#pragma unroll
        for (int p = 0; p < 4; ++p) {
            int r = p * 32 + sr;
            load_lds16(&ctxb[(size_t)(m0 + r) * kD + k0 + sc * 8],
                       &As[(p * 256 + wave * 64) * 8]);
            load_lds16(&Wto[(size_t)(n0 + r) * kD + k0 + sc * 8],
                       &Bs[(p * 256 + wave * 64) * 8]);
        }
        __syncthreads();
#pragma unroll
        for (int kk = 0; kk < 2; ++kk) {
            bf16x8 a[4], b[4];
#pragma unroll
            for (int i = 0; i < 4; ++i)
                a[i] = *(const bf16x8*)&As[(wm * 64 + i * 16 + lr) * 64 + kk * 32 + quad * 8];
#pragma unroll
            for (int nt = 0; nt < 4; ++nt)
                b[nt] = *(const bf16x8*)&Bs[(wn * 64 + nt * 16 + lr) * 64 + kk * 32 + quad * 8];
#pragma unroll
            for (int i = 0; i < 4; ++i)
#pragma unroll
                for (int nt = 0; nt < 4; ++nt)
                    acc[i][nt] = mfma16x16x32(a[i], b[nt], acc[i][nt]);
        }
    }

#pragma unroll
    for (int nt = 0; nt < 4; ++nt) {
        int n = n0 + wn * 64 + nt * 16 + lr;
        float bias = bo[n];
#pragma unroll
        for (int i = 0; i < 4; ++i)
#pragma unroll
            for (int j = 0; j < 4; ++j) {
                int m = m0 + wm * 64 + i * 16 + quad * 4 + j;
                out[(size_t)m * kD + n] = acc[i][nt][j] + bias;
            }
    }
}

// ---------------------------------------------------------------------------
extern "C" void kernel_launch(void* const* d_in, const int* in_sizes, int n_in,
                              void* d_out, int out_size, void* d_ws, size_t ws_size,
                              hipStream_t stream) {
    const float* x  = (const float*)d_in[0];
    const float* Wq = (const float*)d_in[1];
    const float* Wk = (const float*)d_in[2];
    const float* Wv = (const float*)d_in[3];
    const float* Wo = (const float*)d_in[4];
    const float* bo = (const float*)d_in[5];
    float* out = (float*)d_out;

    const size_t n_x   = (size_t)kB * kS * kD;       // 8,388,608
    const size_t n_w   = (size_t)4 * kD * kD;        // 4,194,304
    const size_t n_mat = (size_t)kB * kH * kS * kHD; // 8,388,608

    bf16* xb  = (bf16*)d_ws;        // 16 MB (reused as ctx after qkv_gemm)
    bf16* Wt  = xb + n_x;           // 8 MB
    bf16* Qm  = Wt + n_w;           // 16 MB [B,H,S,HD]
    bf16* Km  = Qm + n_mat;         // 16 MB [B,H,S,HD]
    bf16* Vt  = Km + n_mat;         // 16 MB [B,H,HD,S]
    bf16* ctx = xb;                 // reuse: x dead after qkv_gemm

    prep_x<<<dim3((int)(n_x / (256 * 8))), dim3(256), 0, stream>>>(x, xb);
    prep_w<<<dim3(16, 16, 4), dim3(256), 0, stream>>>(Wq, Wk, Wv, Wo, Wt);
    qkv_gemm<<<dim3(8192 / 128, 3072 / 128), dim3(256), 0, stream>>>(xb, Wt, Qm, Km, Vt);
    attn<<<dim3(kB * kH, 16), dim3(256), 0, stream>>>(Qm, Km, Vt, ctx);
    out_gemm<<<dim3(8192 / 128, 1024 / 128), dim3(256), 0, stream>>>(
        ctx, Wt + (size_t)3 * kD * kD, bo, out);
}

// Round 4
// 432.030 us; speedup vs baseline: 1.0143x; 1.0143x over previous
//
#include <hip/hip_runtime.h>
#include <math.h>
#include <stdint.h>

constexpr int kB = 4;
constexpr int kS = 2048;
constexpr int kD = 1024;
constexpr int kH = 16;
constexpr int kHD = 64;

typedef __bf16 bf16;
typedef __attribute__((ext_vector_type(4))) __bf16 bf16x4;
typedef __attribute__((ext_vector_type(8))) __bf16 bf16x8;
typedef __attribute__((ext_vector_type(4))) float f32x4;

__device__ __forceinline__ f32x4 mfma16x16x32(bf16x8 a, bf16x8 b, f32x4 c) {
    return __builtin_amdgcn_mfma_f32_16x16x32_bf16(a, b, c, 0, 0, 0);
}

#if __has_builtin(__builtin_amdgcn_exp2f)
#define EXP2F(x) __builtin_amdgcn_exp2f(x)
#else
#define EXP2F(x) exp2f(x)
#endif

// async 16B global->LDS. lds base must be wave-uniform; HW adds lane*16.
__device__ __forceinline__ void load_lds16(const bf16* g, bf16* lds) {
    __builtin_amdgcn_global_load_lds(
        (const __attribute__((address_space(1))) void*)g,
        (__attribute__((address_space(3))) void*)lds, 16, 0, 0);
}

// ---------------------------------------------------------------------------
// prep_x: fp32 -> bf16 convert of x (8192x1024).
// ---------------------------------------------------------------------------
__global__ __launch_bounds__(256) void prep_x(const float* __restrict__ x,
                                              bf16* __restrict__ xb) {
    size_t i = ((size_t)blockIdx.x * 256 + threadIdx.x) * 8;
    float4 f0 = *(const float4*)(x + i);
    float4 f1 = *(const float4*)(x + i + 4);
    bf16x8 v;
    v[0] = (bf16)f0.x; v[1] = (bf16)f0.y; v[2] = (bf16)f0.z; v[3] = (bf16)f0.w;
    v[4] = (bf16)f1.x; v[5] = (bf16)f1.y; v[6] = (bf16)f1.z; v[7] = (bf16)f1.w;
    *(bf16x8*)(xb + i) = v;
}

// ---------------------------------------------------------------------------
// prep_w: Wt[z*1024 + n][k] = W_z[k][n] * scale_z (bf16, transposed)
// z=0 Wq scaled by 0.125*log2(e) (exp2-domain softmax), 1=Wk, 2=Wv, 3=Wo.
// ---------------------------------------------------------------------------
__global__ __launch_bounds__(256) void prep_w(const float* __restrict__ Wq,
                                              const float* __restrict__ Wk,
                                              const float* __restrict__ Wv,
                                              const float* __restrict__ Wo,
                                              bf16* __restrict__ Wt) {
    __shared__ bf16 t[64 * 72];
    const int z = blockIdx.z;
    const float* W = (z == 0) ? Wq : (z == 1) ? Wk : (z == 2) ? Wv : Wo;
    const float scale = (z == 0) ? 0.18033688011112042f : 1.0f;
    const int k0 = blockIdx.x * 64, n0 = blockIdx.y * 64;
    const int tid = threadIdx.x;
    for (int p = 0; p < 16; ++p) {
        int idx = tid + p * 256;
        int r = idx >> 6, c = idx & 63;
        t[r * 72 + c] = (bf16)(W[(size_t)(k0 + r) * kD + n0 + c] * scale);
    }
    __syncthreads();
    for (int p = 0; p < 16; ++p) {
        int idx = tid + p * 256;
        int r = idx >> 6, c = idx & 63;
        Wt[(size_t)(z * 1024 + n0 + r) * kD + k0 + c] = t[c * 72 + r];
    }
}

// ---------------------------------------------------------------------------
// qkv_gemm: m97 structure. 128x128 tile, BK=64, unpadded LDS, staged via
// global_load_lds width=16.  4 waves 2x2, each 64x64.
// Q,K -> [B,H,S,HD]; V -> transposed [B,H,HD,S].
// ---------------------------------------------------------------------------
__global__ __launch_bounds__(256) void qkv_gemm(
    const bf16* __restrict__ xb, const bf16* __restrict__ Wt,
    bf16* __restrict__ qo, bf16* __restrict__ ko, bf16* __restrict__ vto)
{
    __shared__ bf16 As[128 * 64];
    __shared__ bf16 Bs[128 * 64];

    const int tid  = threadIdx.x;
    const int wave = tid >> 6;
    const int lane = tid & 63;
    const int quad = lane >> 4;
    const int lr   = lane & 15;
    const int wm   = wave >> 1, wn = wave & 1;

    const int m0 = blockIdx.x * 128;
    const int n0 = blockIdx.y * 128;

    const int sr = tid >> 3, sc = tid & 7;   // staging row/16B-block (per p: +32 rows)

    f32x4 acc[4][4];
#pragma unroll
    for (int i = 0; i < 4; ++i)
#pragma unroll
        for (int nt = 0; nt < 4; ++nt) acc[i][nt] = f32x4{0.f, 0.f, 0.f, 0.f};

    for (int k0 = 0; k0 < kD; k0 += 64) {
        __syncthreads();
#pragma unroll
        for (int p = 0; p < 4; ++p) {
            int r = p * 32 + sr;
            load_lds16(&xb[(size_t)(m0 + r) * kD + k0 + sc * 8],
                       &As[(p * 256 + wave * 64) * 8]);
            load_lds16(&Wt[(size_t)(n0 + r) * kD + k0 + sc * 8],
                       &Bs[(p * 256 + wave * 64) * 8]);
        }
        __syncthreads();
#pragma unroll
        for (int kk = 0; kk < 2; ++kk) {
            bf16x8 a[4], b[4];
#pragma unroll
            for (int i = 0; i < 4; ++i)
                a[i] = *(const bf16x8*)&As[(wm * 64 + i * 16 + lr) * 64 + kk * 32 + quad * 8];
#pragma unroll
            for (int nt = 0; nt < 4; ++nt)
                b[nt] = *(const bf16x8*)&Bs[(wn * 64 + nt * 16 + lr) * 64 + kk * 32 + quad * 8];
#pragma unroll
            for (int i = 0; i < 4; ++i)
#pragma unroll
                for (int nt = 0; nt < 4; ++nt)
                    acc[i][nt] = mfma16x16x32(a[i], b[nt], acc[i][nt]);
        }
    }

    const int w_idx = n0 >> 10;               // 0=Q,1=K,2=V (uniform per block)
    if (w_idx < 2) {
        bf16* dst = (w_idx == 0) ? qo : ko;   // [B,H,S,HD]
#pragma unroll
        for (int i = 0; i < 4; ++i)
#pragma unroll
            for (int nt = 0; nt < 4; ++nt) {
                int n   = n0 + wn * 64 + nt * 16 + lr;
                int col = n & 1023, h = col >> 6, hd = col & 63;
#pragma unroll
                for (int j = 0; j < 4; ++j) {
                    int m = m0 + wm * 64 + i * 16 + quad * 4 + j;
                    int b = m >> 11, s = m & 2047;
                    dst[((size_t)(b * kH + h) * kS + s) * kHD + hd] = (bf16)acc[i][nt][j];
                }
            }
    } else {
        // V transposed: [B,H,HD,S]; j walks s -> bf16x4 stores
#pragma unroll
        for (int i = 0; i < 4; ++i)
#pragma unroll
            for (int nt = 0; nt < 4; ++nt) {
                int n   = n0 + wn * 64 + nt * 16 + lr;
                int col = n & 1023, h = col >> 6, hd = col & 63;
                int mb  = m0 + wm * 64 + i * 16 + quad * 4;
                int b = mb >> 11, s = mb & 2047;
                bf16x4 pk;
#pragma unroll
                for (int j = 0; j < 4; ++j) pk[j] = (bf16)acc[i][nt][j];
                *(bf16x4*)&vto[((size_t)(b * kH + h) * kHD + hd) * kS + s] = pk;
            }
    }
}

// ---------------------------------------------------------------------------
// attn v7: split-K (flash-decoding style).  v5's proven per-wave body
// (2 waves x 32 rows, 64-row q-block, swapped QK^T, P via per-wave LDS),
// ONE job per block:
//   jobs y=0..31  : q-blocks 16..31 split into two k-chunks (<=16 tiles),
//                   partial (o,l) -> f32 scratch.
//   jobs y=32..47 : q-blocks 15..0 unsplit (<=16 tiles), write ctx directly.
// Unnormalized exp2-domain accumulation => partials combine by pure addition
// (order-free).  3072 blocks x 2 waves = 6144 waves, all jobs <=16 tiles,
// heavy first, 8 blocks/CU resident -> sustained ~4 waves/SIMD w/ backfill.
// __launch_bounds__(128,4) caps VGPR at 128 (no K ping-pong -> ~110 needed).
// ---------------------------------------------------------------------------
__global__ __launch_bounds__(128, 4) void attn(
    const bf16* __restrict__ q, const bf16* __restrict__ k,
    const bf16* __restrict__ vt, bf16* __restrict__ ctx,
    float* __restrict__ scr)
{
    __shared__ bf16 Pl[2][2][32 * 72];   // [wave][buf][qrow*72+key]

    const int tid  = threadIdx.x;
    const int wave = tid >> 6;
    const int lane = tid & 63;
    const int quad = lane >> 4;
    const int lr   = lane & 15;

    const int bh = blockIdx.x;
    const int y  = blockIdx.y;           // job id 0..47

    int qb, t0, t1;
    bool split;
    if (y < 32) {                        // split halves of q-blocks 16..31
        qb = 16 + (y >> 1);
        const int c = y & 1;
        const int T = qb + 1, half = (T + 1) >> 1;
        t0 = c ? half : 0;
        t1 = c ? T : half;
        split = true;
    } else {                             // unsplit q-blocks 15..0
        qb = 47 - y;
        t0 = 0; t1 = qb + 1;
        split = false;
    }

    const bf16* qb_p = q  + (size_t)bh * kS * kHD;
    const bf16* kb_p = k  + (size_t)bh * kS * kHD;
    const bf16* vt_p = vt + (size_t)bh * kHD * kS; // [hd][s]

    bf16x8 ones;
#pragma unroll
    for (int i = 0; i < 8; ++i) ones[i] = (bf16)1.0f;

    // per-lane base element offsets
    const size_t koff = (size_t)lr * kHD + quad * 8;   // + kt*64*64 + nt*1024 + kk*32
    const size_t voff = (size_t)lr * kS + quad * 8;    // + nt*16*2048 + kt*64 + kk*32
    bf16* Pw = &Pl[wave][0][0];

    const int base = qb * 64 + wave * 32;              // first q-row of this wave

    bf16x8 aq[2][2];
#pragma unroll
    for (int g = 0; g < 2; ++g)
#pragma unroll
        for (int kk = 0; kk < 2; ++kk)
            aq[g][kk] = *(const bf16x8*)&qb_p[(size_t)(base + g * 16 + lr) * kHD + kk * 32 + quad * 8];

    f32x4 o[2][4];
    f32x4 lacc[2];
#pragma unroll
    for (int g = 0; g < 2; ++g) {
        lacc[g] = f32x4{0.f, 0.f, 0.f, 0.f};
#pragma unroll
        for (int nt = 0; nt < 4; ++nt) o[g][nt] = f32x4{0.f, 0.f, 0.f, 0.f};
    }

#pragma unroll 1
    for (int kt = t0; kt < t1; ++kt) {
        const int k0 = kt * 64;
        bf16* Pb = Pw + (kt & 1) * (32 * 72);

        bf16x8 kf[4][2], vf[4][2];
#pragma unroll
        for (int nt = 0; nt < 4; ++nt) {
            const bf16* kr = kb_p + koff + (size_t)k0 * kHD + nt * 1024;
            kf[nt][0] = *(const bf16x8*)kr;
            kf[nt][1] = *(const bf16x8*)(kr + 32);
            const bf16* vr = vt_p + voff + (size_t)nt * 16 * kS + k0;
            vf[nt][0] = *(const bf16x8*)vr;
            vf[nt][1] = *(const bf16x8*)(vr + 32);
        }

        const bool lastt = (kt == qb);   // last tile of the FULL row (diag tile)
#pragma unroll
        for (int g = 0; g < 2; ++g) {
            // swapped operands: lane holds q-row = base+g*16+lr,
            // keys k0 + nt*16 + quad*4 + j  (4 consecutive keys per reg)
            f32x4 sg[4];
#pragma unroll
            for (int nt = 0; nt < 4; ++nt) {
                sg[nt] = mfma16x16x32(kf[nt][0], aq[g][0], f32x4{0.f, 0.f, 0.f, 0.f});
                sg[nt] = mfma16x16x32(kf[nt][1], aq[g][1], sg[nt]);
            }
            if (lastt) {
                const int qg = base + g * 16 + lr;
#pragma unroll
                for (int nt = 0; nt < 4; ++nt) {
                    bf16x4 pk;
#pragma unroll
                    for (int j = 0; j < 4; ++j) {
                        float s = sg[nt][j];
                        s = (k0 + nt * 16 + quad * 4 + j > qg) ? -3.0e38f : s;
                        pk[j] = (bf16)EXP2F(s);
                    }
                    *(bf16x4*)&Pb[(g * 16 + lr) * 72 + nt * 16 + quad * 4] = pk;
                }
            } else {
#pragma unroll
                for (int nt = 0; nt < 4; ++nt) {
                    bf16x4 pk;
#pragma unroll
                    for (int j = 0; j < 4; ++j) pk[j] = (bf16)EXP2F(sg[nt][j]);
                    *(bf16x4*)&Pb[(g * 16 + lr) * 72 + nt * 16 + quad * 4] = pk;
                }
            }
        }

        // O += P @ V ; l += P @ ones   (P read back in A-operand layout)
#pragma unroll
        for (int g = 0; g < 2; ++g)
#pragma unroll
            for (int kk = 0; kk < 2; ++kk) {
                bf16x8 pa = *(const bf16x8*)&Pb[(g * 16 + lr) * 72 + kk * 32 + quad * 8];
                lacc[g] = mfma16x16x32(pa, ones, lacc[g]);
#pragma unroll
                for (int nt = 0; nt < 4; ++nt)
                    o[g][nt] = mfma16x16x32(pa, vf[nt][kk], o[g][nt]);
            }
    }

    if (!split) {
        // finalize: ctx [B,S,D] bf16, column h*64+hd
        const int b = bh >> 4;
        const int h = bh & 15;
#pragma unroll
        for (int g = 0; g < 2; ++g) {
            float inv[4];
#pragma unroll
            for (int j = 0; j < 4; ++j) inv[j] = 1.0f / lacc[g][j];
#pragma unroll
            for (int nt = 0; nt < 4; ++nt) {
                int hd = nt * 16 + lr;
#pragma unroll
                for (int j = 0; j < 4; ++j) {
                    int qg = base + g * 16 + quad * 4 + j;
                    ctx[((size_t)(b * kS + qg)) * kD + h * kHD + hd] = (bf16)(o[g][nt][j] * inv[j]);
                }
            }
        }
    } else {
        // partial (o,l) -> scratch slot.  slot = (bh*16 + qb-16)*2 + c
        const int c = y & 1;
        float* so = scr + (size_t)((bh * 16 + (qb - 16)) * 2 + c) * 4160;
#pragma unroll
        for (int g = 0; g < 2; ++g)
#pragma unroll
            for (int nt = 0; nt < 4; ++nt)
#pragma unroll
                for (int j = 0; j < 4; ++j)
                    so[(wave * 32 + g * 16 + quad * 4 + j) * 64 + nt * 16 + lr] = o[g][nt][j];
        if (lr == 0) {
#pragma unroll
            for (int g = 0; g < 2; ++g)
#pragma unroll
                for (int j = 0; j < 4; ++j)
                    so[4096 + wave * 32 + g * 16 + quad * 4 + j] = lacc[g][j];
        }
    }
}

// ---------------------------------------------------------------------------
// attn_combine: rows of q-blocks 16..31: ctx = (o0+o1) / (l0+l1).
// ---------------------------------------------------------------------------
__global__ __launch_bounds__(256) void attn_combine(const float* __restrict__ scr,
                                                    bf16* __restrict__ ctx) {
    const int bh = blockIdx.x;
    const int qq = blockIdx.y;           // 0..15 -> qb = 16+qq
    const int qb = 16 + qq;
    const float* s0 = scr + (size_t)((bh * 16 + qq) * 2) * 4160;
    const float* s1 = s0 + 4160;
    const int b = bh >> 4, h = bh & 15;

    __shared__ float invl[64];
    if (threadIdx.x < 64)
        invl[threadIdx.x] = 1.0f / (s0[4096 + threadIdx.x] + s1[4096 + threadIdx.x]);
    __syncthreads();

    for (int e = threadIdx.x; e < 4096; e += 256) {
        int row = e >> 6, d = e & 63;
        float v = (s0[e] + s1[e]) * invl[row];
        ctx[((size_t)(b * kS + qb * 64 + row)) * kD + h * kHD + d] = (bf16)v;
    }
}

// ---------------------------------------------------------------------------
// out_gemm: out = ctx @ Wo + bo (fp32).  Same m97 structure.
// ---------------------------------------------------------------------------
__global__ __launch_bounds__(256) void out_gemm(
    const bf16* __restrict__ ctxb, const bf16* __restrict__ Wto,
    const float* __restrict__ bo, float* __restrict__ out)
{
    __shared__ bf16 As[128 * 64];
    __shared__ bf16 Bs[128 * 64];

    const int tid  = threadIdx.x;
    const int wave = tid >> 6;
    const int lane = tid & 63;
    const int quad = lane >> 4;
    const int lr   = lane & 15;
    const int wm   = wave >> 1, wn = wave & 1;

    const int m0 = blockIdx.x * 128;
    const int n0 = blockIdx.y * 128;

    const int sr = tid >> 3, sc = tid & 7;

    f32x4 acc[4][4];
#pragma unroll
    for (int i = 0; i < 4; ++i)
#pragma unroll
        for (int nt = 0; nt < 4; ++nt) acc[i][nt] = f32x4{0.f, 0.f, 0.f, 0.f};

    for (int k0 = 0; k0 < kD; k0 += 64) {
        __syncthreads();
#pragma unroll
        for (int p = 0; p < 4; ++p) {
            int r = p * 32 + sr;
            load_lds16(&ctxb[(size_t)(m0 + r) * kD + k0 + sc * 8],
                       &As[(p * 256 + wave * 64) * 8]);
            load_lds16(&Wto[(size_t)(n0 + r) * kD + k0 + sc * 8],
                       &Bs[(p * 256 + wave * 64) * 8]);
        }
        __syncthreads();
#pragma unroll
        for (int kk = 0; kk < 2; ++kk) {
            bf16x8 a[4], b[4];
#pragma unroll
            for (int i = 0; i < 4; ++i)
                a[i] = *(const bf16x8*)&As[(wm * 64 + i * 16 + lr) * 64 + kk * 32 + quad * 8];
#pragma unroll
            for (int nt = 0; nt < 4; ++nt)
                b[nt] = *(const bf16x8*)&Bs[(wn * 64 + nt * 16 + lr) * 64 + kk * 32 + quad * 8];
#pragma unroll
            for (int i = 0; i < 4; ++i)
#pragma unroll
                for (int nt = 0; nt < 4; ++nt)
                    acc[i][nt] = mfma16x16x32(a[i], b[nt], acc[i][nt]);
        }
    }

#pragma unroll
    for (int nt = 0; nt < 4; ++nt) {
        int n = n0 + wn * 64 + nt * 16 + lr;
        float bias = bo[n];
#pragma unroll
        for (int i = 0; i < 4; ++i)
#pragma unroll
            for (int j = 0; j < 4; ++j) {
                int m = m0 + wm * 64 + i * 16 + quad * 4 + j;
                out[(size_t)m * kD + n] = acc[i][nt][j] + bias;
            }
    }
}

// ---------------------------------------------------------------------------
extern "C" void kernel_launch(void* const* d_in, const int* in_sizes, int n_in,
                              void* d_out, int out_size, void* d_ws, size_t ws_size,
                              hipStream_t stream) {
    const float* x  = (const float*)d_in[0];
    const float* Wq = (const float*)d_in[1];
    const float* Wk = (const float*)d_in[2];
    const float* Wv = (const float*)d_in[3];
    const float* Wo = (const float*)d_in[4];
    const float* bo = (const float*)d_in[5];
    float* out = (float*)d_out;

    const size_t n_x   = (size_t)kB * kS * kD;       // 8,388,608
    const size_t n_w   = (size_t)4 * kD * kD;        // 4,194,304
    const size_t n_mat = (size_t)kB * kH * kS * kHD; // 8,388,608

    bf16* xb  = (bf16*)d_ws;        // 16 MB (reused as ctx after qkv_gemm)
    bf16* Wt  = xb + n_x;           // 8 MB
    bf16* Qm  = Wt + n_w;           // 16 MB [B,H,S,HD]
    bf16* Km  = Qm + n_mat;         // 16 MB [B,H,S,HD]
    bf16* Vt  = Km + n_mat;         // 16 MB [B,H,HD,S]
    float* scr = (float*)(Vt + n_mat); // 34 MB split-k scratch (2048 x 4160 f32)
    bf16* ctx = xb;                 // reuse: x dead after qkv_gemm

    prep_x<<<dim3((int)(n_x / (256 * 8))), dim3(256), 0, stream>>>(x, xb);
    prep_w<<<dim3(16, 16, 4), dim3(256), 0, stream>>>(Wq, Wk, Wv, Wo, Wt);
    qkv_gemm<<<dim3(8192 / 128, 3072 / 128), dim3(256), 0, stream>>>(xb, Wt, Qm, Km, Vt);
    attn<<<dim3(kB * kH, 48), dim3(128), 0, stream>>>(Qm, Km, Vt, ctx, scr);
    attn_combine<<<dim3(kB * kH, 16), dim3(256), 0, stream>>>(scr, ctx);
    out_gemm<<<dim3(8192 / 128, 1024 / 128), dim3(256), 0, stream>>>(
        ctx, Wt + (size_t)3 * kD * kD, bo, out);
}

// Round 5
// 339.705 us; speedup vs baseline: 1.2900x; 1.2718x over previous
//
#include <hip/hip_runtime.h>
#include <math.h>
#include <stdint.h>

constexpr int kB = 4;
constexpr int kS = 2048;
constexpr int kD = 1024;
constexpr int kH = 16;
constexpr int kHD = 64;

typedef __bf16 bf16;
typedef __attribute__((ext_vector_type(4))) __bf16 bf16x4;
typedef __attribute__((ext_vector_type(8))) __bf16 bf16x8;
typedef __attribute__((ext_vector_type(4))) float f32x4;

__device__ __forceinline__ f32x4 mfma16x16x32(bf16x8 a, bf16x8 b, f32x4 c) {
    return __builtin_amdgcn_mfma_f32_16x16x32_bf16(a, b, c, 0, 0, 0);
}

#if __has_builtin(__builtin_amdgcn_exp2f)
#define EXP2F(x) __builtin_amdgcn_exp2f(x)
#else
#define EXP2F(x) exp2f(x)
#endif

// async 16B global->LDS. lds base must be wave-uniform; HW adds lane*16.
__device__ __forceinline__ void load_lds16(const bf16* g, bf16* lds) {
    __builtin_amdgcn_global_load_lds(
        (const __attribute__((address_space(1))) void*)g,
        (__attribute__((address_space(3))) void*)lds, 16, 0, 0);
}

// ---------------------------------------------------------------------------
// prep_x: fp32 -> bf16 convert of x (8192x1024).
// ---------------------------------------------------------------------------
__global__ __launch_bounds__(256) void prep_x(const float* __restrict__ x,
                                              bf16* __restrict__ xb) {
    size_t i = ((size_t)blockIdx.x * 256 + threadIdx.x) * 8;
    float4 f0 = *(const float4*)(x + i);
    float4 f1 = *(const float4*)(x + i + 4);
    bf16x8 v;
    v[0] = (bf16)f0.x; v[1] = (bf16)f0.y; v[2] = (bf16)f0.z; v[3] = (bf16)f0.w;
    v[4] = (bf16)f1.x; v[5] = (bf16)f1.y; v[6] = (bf16)f1.z; v[7] = (bf16)f1.w;
    *(bf16x8*)(xb + i) = v;
}

// ---------------------------------------------------------------------------
// prep_w: Wt[z*1024 + n][k] = W_z[k][n] * scale_z (bf16, transposed)
// z=0 Wq scaled by 0.125*log2(e) (exp2-domain softmax), 1=Wk, 2=Wv, 3=Wo.
// ---------------------------------------------------------------------------
__global__ __launch_bounds__(256) void prep_w(const float* __restrict__ Wq,
                                              const float* __restrict__ Wk,
                                              const float* __restrict__ Wv,
                                              const float* __restrict__ Wo,
                                              bf16* __restrict__ Wt) {
    __shared__ bf16 t[64 * 72];
    const int z = blockIdx.z;
    const float* W = (z == 0) ? Wq : (z == 1) ? Wk : (z == 2) ? Wv : Wo;
    const float scale = (z == 0) ? 0.18033688011112042f : 1.0f;
    const int k0 = blockIdx.x * 64, n0 = blockIdx.y * 64;
    const int tid = threadIdx.x;
    for (int p = 0; p < 16; ++p) {
        int idx = tid + p * 256;
        int r = idx >> 6, c = idx & 63;
        t[r * 72 + c] = (bf16)(W[(size_t)(k0 + r) * kD + n0 + c] * scale);
    }
    __syncthreads();
    for (int p = 0; p < 16; ++p) {
        int idx = tid + p * 256;
        int r = idx >> 6, c = idx & 63;
        Wt[(size_t)(z * 1024 + n0 + r) * kD + k0 + c] = t[c * 72 + r];
    }
}

// ---------------------------------------------------------------------------
// qkv_gemm: m97 structure. 128x128 tile, BK=64, unpadded LDS, staged via
// global_load_lds width=16.  4 waves 2x2, each 64x64.
// Q,K -> [B,H,S,HD]; V -> transposed [B,H,HD,S].
// ---------------------------------------------------------------------------
__global__ __launch_bounds__(256) void qkv_gemm(
    const bf16* __restrict__ xb, const bf16* __restrict__ Wt,
    bf16* __restrict__ qo, bf16* __restrict__ ko, bf16* __restrict__ vto)
{
    __shared__ bf16 As[128 * 64];
    __shared__ bf16 Bs[128 * 64];

    const int tid  = threadIdx.x;
    const int wave = tid >> 6;
    const int lane = tid & 63;
    const int quad = lane >> 4;
    const int lr   = lane & 15;
    const int wm   = wave >> 1, wn = wave & 1;

    const int m0 = blockIdx.x * 128;
    const int n0 = blockIdx.y * 128;

    const int sr = tid >> 3, sc = tid & 7;   // staging row/16B-block (per p: +32 rows)

    f32x4 acc[4][4];
#pragma unroll
    for (int i = 0; i < 4; ++i)
#pragma unroll
        for (int nt = 0; nt < 4; ++nt) acc[i][nt] = f32x4{0.f, 0.f, 0.f, 0.f};

    for (int k0 = 0; k0 < kD; k0 += 64) {
        __syncthreads();
#pragma unroll
        for (int p = 0; p < 4; ++p) {
            int r = p * 32 + sr;
            load_lds16(&xb[(size_t)(m0 + r) * kD + k0 + sc * 8],
                       &As[(p * 256 + wave * 64) * 8]);
            load_lds16(&Wt[(size_t)(n0 + r) * kD + k0 + sc * 8],
                       &Bs[(p * 256 + wave * 64) * 8]);
        }
        __syncthreads();
#pragma unroll
        for (int kk = 0; kk < 2; ++kk) {
            bf16x8 a[4], b[4];
#pragma unroll
            for (int i = 0; i < 4; ++i)
                a[i] = *(const bf16x8*)&As[(wm * 64 + i * 16 + lr) * 64 + kk * 32 + quad * 8];
#pragma unroll
            for (int nt = 0; nt < 4; ++nt)
                b[nt] = *(const bf16x8*)&Bs[(wn * 64 + nt * 16 + lr) * 64 + kk * 32 + quad * 8];
#pragma unroll
            for (int i = 0; i < 4; ++i)
#pragma unroll
                for (int nt = 0; nt < 4; ++nt)
                    acc[i][nt] = mfma16x16x32(a[i], b[nt], acc[i][nt]);
        }
    }

    const int w_idx = n0 >> 10;               // 0=Q,1=K,2=V (uniform per block)
    if (w_idx < 2) {
        bf16* dst = (w_idx == 0) ? qo : ko;   // [B,H,S,HD]
#pragma unroll
        for (int i = 0; i < 4; ++i)
#pragma unroll
            for (int nt = 0; nt < 4; ++nt) {
                int n   = n0 + wn * 64 + nt * 16 + lr;
                int col = n & 1023, h = col >> 6, hd = col & 63;
#pragma unroll
                for (int j = 0; j < 4; ++j) {
                    int m = m0 + wm * 64 + i * 16 + quad * 4 + j;
                    int b = m >> 11, s = m & 2047;
                    dst[((size_t)(b * kH + h) * kS + s) * kHD + hd] = (bf16)acc[i][nt][j];
                }
            }
    } else {
        // V transposed: [B,H,HD,S]; j walks s -> bf16x4 stores
#pragma unroll
        for (int i = 0; i < 4; ++i)
#pragma unroll
            for (int nt = 0; nt < 4; ++nt) {
                int n   = n0 + wn * 64 + nt * 16 + lr;
                int col = n & 1023, h = col >> 6, hd = col & 63;
                int mb  = m0 + wm * 64 + i * 16 + quad * 4;
                int b = mb >> 11, s = mb & 2047;
                bf16x4 pk;
#pragma unroll
                for (int j = 0; j < 4; ++j) pk[j] = (bf16)acc[i][nt][j];
                *(bf16x4*)&vto[((size_t)(b * kH + h) * kHD + hd) * kS + s] = pk;
            }
    }
}

// ---------------------------------------------------------------------------
// attn v8: v5 (best measured: attn 127us) + ONE change: V joins the
// one-tile-ahead register ping-pong.  v5 prefetched K(t+1) during tile t but
// loaded V(t) at the top of tile t, consumed ~300cy later in PV -> V load
// latency sat naked on the critical path every tile.  Now K(t+1),V(t+1) are
// both issued before COMPUTE(t), giving all 32 loads a full tile-compute
// (~1400cy) to land.  VGPR ~220 -> __launch_bounds__(128,2) (occupancy is
// grid-limited at 2 waves/SIMD regardless).
// Everything else identical to v5: 64-row q-blocks (both waves share K/V
// tiles -> FETCH ~29MB), block (bh,p) runs q-blocks 31-p then p (33 tiles
// per block, perfect balance), swapped QK^T, P via per-wave LDS.
// ---------------------------------------------------------------------------
#define LOADK(kf, kt_)                                                         \
    do {                                                                       \
        const bf16* krb = kb_p + koff + (size_t)(kt_) * 64 * kHD;              \
        _Pragma("unroll")                                                      \
        for (int nt = 0; nt < 4; ++nt) {                                       \
            kf[nt][0] = *(const bf16x8*)(krb + nt * 1024);                     \
            kf[nt][1] = *(const bf16x8*)(krb + nt * 1024 + 32);                \
        }                                                                      \
    } while (0)

#define LOADV(vf, kt_)                                                         \
    do {                                                                       \
        const bf16* vrb = vt_p + voff + (kt_) * 64;                            \
        _Pragma("unroll")                                                      \
        for (int nt = 0; nt < 4; ++nt) {                                       \
            vf[nt][0] = *(const bf16x8*)(vrb + (size_t)nt * 16 * kS);          \
            vf[nt][1] = *(const bf16x8*)(vrb + (size_t)nt * 16 * kS + 32);     \
        }                                                                      \
    } while (0)

#define COMPUTE(kf, vf, kt_)                                                   \
    do {                                                                       \
        const int k0 = (kt_) * 64;                                             \
        bf16* Pb = Pw + ((kt_) & 1) * (32 * 72);                               \
        const bool lastt = ((kt_) == T - 1);                                   \
        _Pragma("unroll")                                                      \
        for (int g = 0; g < 2; ++g) {                                          \
            f32x4 sg[4];                                                       \
            _Pragma("unroll")                                                  \
            for (int nt = 0; nt < 4; ++nt) {                                   \
                sg[nt] = mfma16x16x32(kf[nt][0], aq[g][0],                     \
                                      f32x4{0.f, 0.f, 0.f, 0.f});              \
                sg[nt] = mfma16x16x32(kf[nt][1], aq[g][1], sg[nt]);            \
            }                                                                  \
            if (lastt) {                                                       \
                const int qg = base + g * 16 + lr;                             \
                _Pragma("unroll")                                              \
                for (int nt = 0; nt < 4; ++nt) {                               \
                    bf16x4 pk;                                                 \
                    _Pragma("unroll")                                          \
                    for (int j = 0; j < 4; ++j) {                              \
                        float s = sg[nt][j];                                   \
                        s = (k0 + nt * 16 + quad * 4 + j > qg) ? -3.0e38f : s; \
                        pk[j] = (bf16)EXP2F(s);                                \
                    }                                                          \
                    *(bf16x4*)&Pb[(g * 16 + lr) * 72 + nt * 16 + quad * 4] = pk; \
                }                                                              \
            } else {                                                           \
                _Pragma("unroll")                                              \
                for (int nt = 0; nt < 4; ++nt) {                               \
                    bf16x4 pk;                                                 \
                    _Pragma("unroll")                                          \
                    for (int j = 0; j < 4; ++j) pk[j] = (bf16)EXP2F(sg[nt][j]); \
                    *(bf16x4*)&Pb[(g * 16 + lr) * 72 + nt * 16 + quad * 4] = pk; \
                }                                                              \
            }                                                                  \
        }                                                                      \
        _Pragma("unroll")                                                      \
        for (int g = 0; g < 2; ++g)                                            \
            _Pragma("unroll")                                                  \
            for (int kk = 0; kk < 2; ++kk) {                                   \
                bf16x8 pa = *(const bf16x8*)&Pb[(g * 16 + lr) * 72 + kk * 32 + quad * 8]; \
                lacc[g] = mfma16x16x32(pa, ones, lacc[g]);                     \
                _Pragma("unroll")                                              \
                for (int nt = 0; nt < 4; ++nt)                                 \
                    o[g][nt] = mfma16x16x32(pa, vf[nt][kk], o[g][nt]);         \
            }                                                                  \
    } while (0)

__global__ __launch_bounds__(128, 2) void attn(
    const bf16* __restrict__ q, const bf16* __restrict__ k,
    const bf16* __restrict__ vt, bf16* __restrict__ ctx)
{
    __shared__ bf16 Pl[2][2][32 * 72];   // [wave][buf][qrow*72+key]

    const int tid  = threadIdx.x;
    const int wave = tid >> 6;
    const int lane = tid & 63;
    const int quad = lane >> 4;
    const int lr   = lane & 15;

    const int bh = blockIdx.x;
    const int p  = blockIdx.y;           // 0..15

    const bf16* qb_p = q  + (size_t)bh * kS * kHD;
    const bf16* kb_p = k  + (size_t)bh * kS * kHD;
    const bf16* vt_p = vt + (size_t)bh * kHD * kS; // [hd][s]

    bf16x8 ones;
#pragma unroll
    for (int i = 0; i < 8; ++i) ones[i] = (bf16)1.0f;

    // per-lane base element offsets
    const size_t koff = (size_t)lr * kHD + quad * 8;   // + kt*64*64 + nt*1024 + kk*32
    const size_t voff = (size_t)lr * kS + quad * 8;    // + nt*16*2048 + kt*64 + kk*32
    bf16* Pw = &Pl[wave][0][0];

    const int b = bh >> 4;
    const int h = bh & 15;

#pragma unroll 1
    for (int gi = 0; gi < 2; ++gi) {
        const int qb   = gi ? p : (31 - p);   // q-block 0..31 (heavy first)
        const int T    = qb + 1;              // k-tiles
        const int base = qb * 64 + wave * 32; // first q-row of this wave

        bf16x8 aq[2][2];
#pragma unroll
        for (int g = 0; g < 2; ++g)
#pragma unroll
            for (int kk = 0; kk < 2; ++kk)
                aq[g][kk] = *(const bf16x8*)&qb_p[(size_t)(base + g * 16 + lr) * kHD + kk * 32 + quad * 8];

        f32x4 o[2][4];
        f32x4 lacc[2];
#pragma unroll
        for (int g = 0; g < 2; ++g) {
            lacc[g] = f32x4{0.f, 0.f, 0.f, 0.f};
#pragma unroll
            for (int nt = 0; nt < 4; ++nt) o[g][nt] = f32x4{0.f, 0.f, 0.f, 0.f};
        }

        bf16x8 kfA[4][2], kfB[4][2];
        bf16x8 vfA[4][2], vfB[4][2];
        LOADK(kfA, 0);
        LOADV(vfA, 0);
        int kt = 0;
        while (true) {
            {
                if (kt + 1 < T) { LOADK(kfB, kt + 1); LOADV(vfB, kt + 1); }
                COMPUTE(kfA, vfA, kt);
            }
            if (++kt == T) break;
            {
                if (kt + 1 < T) { LOADK(kfA, kt + 1); LOADV(vfA, kt + 1); }
                COMPUTE(kfB, vfB, kt);
            }
            if (++kt == T) break;
        }

        // ctx [B,S,D] bf16, column h*64+hd
#pragma unroll
        for (int g = 0; g < 2; ++g) {
            float inv[4];
#pragma unroll
            for (int j = 0; j < 4; ++j) inv[j] = 1.0f / lacc[g][j];
#pragma unroll
            for (int nt = 0; nt < 4; ++nt) {
                int hd = nt * 16 + lr;
#pragma unroll
                for (int j = 0; j < 4; ++j) {
                    int qg = base + g * 16 + quad * 4 + j;
                    ctx[((size_t)(b * kS + qg)) * kD + h * kHD + hd] = (bf16)(o[g][nt][j] * inv[j]);
                }
            }
        }
    }
}

// ---------------------------------------------------------------------------
// out_gemm: out = ctx @ Wo + bo (fp32).  Same m97 structure.
// ---------------------------------------------------------------------------
__global__ __launch_bounds__(256) void out_gemm(
    const bf16* __restrict__ ctxb, const bf16* __restrict__ Wto,
    const float* __restrict__ bo, float* __restrict__ out)
{
    __shared__ bf16 As[128 * 64];
    __shared__ bf16 Bs[128 * 64];

    const int tid  = threadIdx.x;
    const int wave = tid >> 6;
    const int lane = tid & 63;
    const int quad = lane >> 4;
    const int lr   = lane & 15;
    const int wm   = wave >> 1, wn = wave & 1;

    const int m0 = blockIdx.x * 128;
    const int n0 = blockIdx.y * 128;

    const int sr = tid >> 3, sc = tid & 7;

    f32x4 acc[4][4];
#pragma unroll
    for (int i = 0; i < 4; ++i)
#pragma unroll
        for (int nt = 0; nt < 4; ++nt) acc[i][nt] = f32x4{0.f, 0.f, 0.f, 0.f};

    for (int k0 = 0; k0 < kD; k0 += 64) {
        __syncthreads();
#pragma unroll
        for (int p = 0; p < 4; ++p) {
            int r = p * 32 + sr;
            load_lds16(&ctxb[(size_t)(m0 + r) * kD + k0 + sc * 8],
                       &As[(p * 256 + wave * 64) * 8]);
            load_lds16(&Wto[(size_t)(n0 + r) * kD + k0 + sc * 8],
                       &Bs[(p * 256 + wave * 64) * 8]);
        }
        __syncthreads();
#pragma unroll
        for (int kk = 0; kk < 2; ++kk) {
            bf16x8 a[4], b[4];
#pragma unroll
            for (int i = 0; i < 4; ++i)
                a[i] = *(const bf16x8*)&As[(wm * 64 + i * 16 + lr) * 64 + kk * 32 + quad * 8];
#pragma unroll
            for (int nt = 0; nt < 4; ++nt)
                b[nt] = *(const bf16x8*)&Bs[(wn * 64 + nt * 16 + lr) * 64 + kk * 32 + quad * 8];
#pragma unroll
            for (int i = 0; i < 4; ++i)
#pragma unroll
                for (int nt = 0; nt < 4; ++nt)
                    acc[i][nt] = mfma16x16x32(a[i], b[nt], acc[i][nt]);
        }
    }

#pragma unroll
    for (int nt = 0; nt < 4; ++nt) {
        int n = n0 + wn * 64 + nt * 16 + lr;
        float bias = bo[n];
#pragma unroll
        for (int i = 0; i < 4; ++i)
#pragma unroll
            for (int j = 0; j < 4; ++j) {
                int m = m0 + wm * 64 + i * 16 + quad * 4 + j;
                out[(size_t)m * kD + n] = acc[i][nt][j] + bias;
            }
    }
}

// ---------------------------------------------------------------------------
extern "C" void kernel_launch(void* const* d_in, const int* in_sizes, int n_in,
                              void* d_out, int out_size, void* d_ws, size_t ws_size,
                              hipStream_t stream) {
    const float* x  = (const float*)d_in[0];
    const float* Wq = (const float*)d_in[1];
    const float* Wk = (const float*)d_in[2];
    const float* Wv = (const float*)d_in[3];
    const float* Wo = (const float*)d_in[4];
    const float* bo = (const float*)d_in[5];
    float* out = (float*)d_out;

    const size_t n_x   = (size_t)kB * kS * kD;       // 8,388,608
    const size_t n_w   = (size_t)4 * kD * kD;        // 4,194,304
    const size_t n_mat = (size_t)kB * kH * kS * kHD; // 8,388,608

    bf16* xb  = (bf16*)d_ws;        // 16 MB (reused as ctx after qkv_gemm)
    bf16* Wt  = xb + n_x;           // 8 MB
    bf16* Qm  = Wt + n_w;           // 16 MB [B,H,S,HD]
    bf16* Km  = Qm + n_mat;         // 16 MB [B,H,S,HD]
    bf16* Vt  = Km + n_mat;         // 16 MB [B,H,HD,S]
    bf16* ctx = xb;                 // reuse: x dead after qkv_gemm

    prep_x<<<dim3((int)(n_x / (256 * 8))), dim3(256), 0, stream>>>(x, xb);
    prep_w<<<dim3(16, 16, 4), dim3(256), 0, stream>>>(Wq, Wk, Wv, Wo, Wt);
    qkv_gemm<<<dim3(8192 / 128, 3072 / 128), dim3(256), 0, stream>>>(xb, Wt, Qm, Km, Vt);
    attn<<<dim3(kB * kH, 16), dim3(128), 0, stream>>>(Qm, Km, Vt, ctx);
    out_gemm<<<dim3(8192 / 128, 1024 / 128), dim3(256), 0, stream>>>(
        ctx, Wt + (size_t)3 * kD * kD, bo, out);
}

// Round 6
// 325.035 us; speedup vs baseline: 1.3482x; 1.0451x over previous
//
#include <hip/hip_runtime.h>
#include <math.h>
#include <stdint.h>

constexpr int kB = 4;
constexpr int kS = 2048;
constexpr int kD = 1024;
constexpr int kH = 16;
constexpr int kHD = 64;

typedef __bf16 bf16;
typedef __attribute__((ext_vector_type(4))) __bf16 bf16x4;
typedef __attribute__((ext_vector_type(8))) __bf16 bf16x8;
typedef __attribute__((ext_vector_type(4))) float f32x4;

__device__ __forceinline__ f32x4 mfma16x16x32(bf16x8 a, bf16x8 b, f32x4 c) {
    return __builtin_amdgcn_mfma_f32_16x16x32_bf16(a, b, c, 0, 0, 0);
}

#if __has_builtin(__builtin_amdgcn_exp2f)
#define EXP2F(x) __builtin_amdgcn_exp2f(x)
#else
#define EXP2F(x) exp2f(x)
#endif

// async 16B global->LDS. lds base must be wave-uniform; HW adds lane*16.
__device__ __forceinline__ void load_lds16(const bf16* g, bf16* lds) {
    __builtin_amdgcn_global_load_lds(
        (const __attribute__((address_space(1))) void*)g,
        (__attribute__((address_space(3))) void*)lds, 16, 0, 0);
}

// ---------------------------------------------------------------------------
// prep_x: fp32 -> bf16 convert of x (8192x1024).
// ---------------------------------------------------------------------------
__global__ __launch_bounds__(256) void prep_x(const float* __restrict__ x,
                                              bf16* __restrict__ xb) {
    size_t i = ((size_t)blockIdx.x * 256 + threadIdx.x) * 8;
    float4 f0 = *(const float4*)(x + i);
    float4 f1 = *(const float4*)(x + i + 4);
    bf16x8 v;
    v[0] = (bf16)f0.x; v[1] = (bf16)f0.y; v[2] = (bf16)f0.z; v[3] = (bf16)f0.w;
    v[4] = (bf16)f1.x; v[5] = (bf16)f1.y; v[6] = (bf16)f1.z; v[7] = (bf16)f1.w;
    *(bf16x8*)(xb + i) = v;
}

// ---------------------------------------------------------------------------
// prep_w: Wt[z*1024 + n][k] = W_z[k][n] * scale_z (bf16, transposed)
// z=0 Wq scaled by 0.125*log2(e) (exp2-domain softmax), 1=Wk, 2=Wv, 3=Wo.
// ---------------------------------------------------------------------------
__global__ __launch_bounds__(256) void prep_w(const float* __restrict__ Wq,
                                              const float* __restrict__ Wk,
                                              const float* __restrict__ Wv,
                                              const float* __restrict__ Wo,
                                              bf16* __restrict__ Wt) {
    __shared__ bf16 t[64 * 72];
    const int z = blockIdx.z;
    const float* W = (z == 0) ? Wq : (z == 1) ? Wk : (z == 2) ? Wv : Wo;
    const float scale = (z == 0) ? 0.18033688011112042f : 1.0f;
    const int k0 = blockIdx.x * 64, n0 = blockIdx.y * 64;
    const int tid = threadIdx.x;
    for (int p = 0; p < 16; ++p) {
        int idx = tid + p * 256;
        int r = idx >> 6, c = idx & 63;
        t[r * 72 + c] = (bf16)(W[(size_t)(k0 + r) * kD + n0 + c] * scale);
    }
    __syncthreads();
    for (int p = 0; p < 16; ++p) {
        int idx = tid + p * 256;
        int r = idx >> 6, c = idx & 63;
        Wt[(size_t)(z * 1024 + n0 + r) * kD + k0 + c] = t[c * 72 + r];
    }
}

// ---------------------------------------------------------------------------
// qkv_gemm: m97 structure. 128x128 tile, BK=64, unpadded LDS, staged via
// global_load_lds width=16.  4 waves 2x2, each 64x64.
// Q,K -> NATURAL [B,S,D] layout (coalesced stores: consecutive lanes ->
// consecutive cols -> 1 cache line per store instr; the old [B,H,S,HD]
// epilogue hit 64 lines per store instr).  V -> transposed [B,H,HD,S].
// ---------------------------------------------------------------------------
__global__ __launch_bounds__(256) void qkv_gemm(
    const bf16* __restrict__ xb, const bf16* __restrict__ Wt,
    bf16* __restrict__ qo, bf16* __restrict__ ko, bf16* __restrict__ vto)
{
    __shared__ bf16 As[128 * 64];
    __shared__ bf16 Bs[128 * 64];

    const int tid  = threadIdx.x;
    const int wave = tid >> 6;
    const int lane = tid & 63;
    const int quad = lane >> 4;
    const int lr   = lane & 15;
    const int wm   = wave >> 1, wn = wave & 1;

    const int m0 = blockIdx.x * 128;
    const int n0 = blockIdx.y * 128;

    const int sr = tid >> 3, sc = tid & 7;   // staging row/16B-block (per p: +32 rows)

    f32x4 acc[4][4];
#pragma unroll
    for (int i = 0; i < 4; ++i)
#pragma unroll
        for (int nt = 0; nt < 4; ++nt) acc[i][nt] = f32x4{0.f, 0.f, 0.f, 0.f};

    for (int k0 = 0; k0 < kD; k0 += 64) {
        __syncthreads();
#pragma unroll
        for (int p = 0; p < 4; ++p) {
            int r = p * 32 + sr;
            load_lds16(&xb[(size_t)(m0 + r) * kD + k0 + sc * 8],
                       &As[(p * 256 + wave * 64) * 8]);
            load_lds16(&Wt[(size_t)(n0 + r) * kD + k0 + sc * 8],
                       &Bs[(p * 256 + wave * 64) * 8]);
        }
        __syncthreads();
#pragma unroll
        for (int kk = 0; kk < 2; ++kk) {
            bf16x8 a[4], b[4];
#pragma unroll
            for (int i = 0; i < 4; ++i)
                a[i] = *(const bf16x8*)&As[(wm * 64 + i * 16 + lr) * 64 + kk * 32 + quad * 8];
#pragma unroll
            for (int nt = 0; nt < 4; ++nt)
                b[nt] = *(const bf16x8*)&Bs[(wn * 64 + nt * 16 + lr) * 64 + kk * 32 + quad * 8];
#pragma unroll
            for (int i = 0; i < 4; ++i)
#pragma unroll
                for (int nt = 0; nt < 4; ++nt)
                    acc[i][nt] = mfma16x16x32(a[i], b[nt], acc[i][nt]);
        }
    }

    const int w_idx = n0 >> 10;               // 0=Q,1=K,2=V (uniform per block)
    if (w_idx < 2) {
        bf16* dst = (w_idx == 0) ? qo : ko;   // [B,S,D] natural layout
#pragma unroll
        for (int i = 0; i < 4; ++i)
#pragma unroll
            for (int nt = 0; nt < 4; ++nt) {
                int n   = n0 + wn * 64 + nt * 16 + lr;
                int col = n & 1023;
#pragma unroll
                for (int j = 0; j < 4; ++j) {
                    int m = m0 + wm * 64 + i * 16 + quad * 4 + j;
                    dst[(size_t)m * kD + col] = (bf16)acc[i][nt][j];
                }
            }
    } else {
        // V transposed: [B,H,HD,S]; j walks s -> bf16x4 stores
#pragma unroll
        for (int i = 0; i < 4; ++i)
#pragma unroll
            for (int nt = 0; nt < 4; ++nt) {
                int n   = n0 + wn * 64 + nt * 16 + lr;
                int col = n & 1023, h = col >> 6, hd = col & 63;
                int mb  = m0 + wm * 64 + i * 16 + quad * 4;
                int b = mb >> 11, s = mb & 2047;
                bf16x4 pk;
#pragma unroll
                for (int j = 0; j < 4; ++j) pk[j] = (bf16)acc[i][nt][j];
                *(bf16x4*)&vto[((size_t)(b * kH + h) * kHD + hd) * kS + s] = pk;
            }
    }
}

// ---------------------------------------------------------------------------
// attn v9: v5's exact loop (best measured: attn 127us, total 325us), with
//  (a) Q/K read directly from the GEMM-natural [B,S,D] layout (per-lane row
//      stride kD instead of kHD; same cache-line count, 100% line use), and
//  (b) s_setprio(1/0) around the MFMA clusters (T5: +4-7% on attn blocks
//      whose waves run un-barriered at different phases, as here).
// Structure: 64-row q-blocks, 2 waves x 32 rows sharing every K/V tile
// (FETCH ~29MB); block (bh,p) runs q-blocks 31-p then p (33 tiles each,
// perfect balance); K(t+1) register ping-pong; V(t) issued at tile top;
// swapped QK^T; P via per-wave LDS; no barriers in the k-loop.
// ---------------------------------------------------------------------------
#define LOADK(kf, kt_)                                                         \
    do {                                                                       \
        const bf16* krb = kb_p + koff + (size_t)((kt_) * 64) * kD;             \
        _Pragma("unroll")                                                      \
        for (int nt = 0; nt < 4; ++nt) {                                       \
            kf[nt][0] = *(const bf16x8*)(krb + (size_t)nt * 16 * kD);          \
            kf[nt][1] = *(const bf16x8*)(krb + (size_t)nt * 16 * kD + 32);     \
        }                                                                      \
    } while (0)

#define LOADV(vf, kt_)                                                         \
    do {                                                                       \
        const bf16* vrb = vt_p + voff + (kt_) * 64;                            \
        _Pragma("unroll")                                                      \
        for (int nt = 0; nt < 4; ++nt) {                                       \
            vf[nt][0] = *(const bf16x8*)(vrb + (size_t)nt * 16 * kS);          \
            vf[nt][1] = *(const bf16x8*)(vrb + (size_t)nt * 16 * kS + 32);     \
        }                                                                      \
    } while (0)

#define COMPUTE(kf, vf, kt_)                                                   \
    do {                                                                       \
        const int k0 = (kt_) * 64;                                             \
        bf16* Pb = Pw + ((kt_) & 1) * (32 * 72);                               \
        const bool lastt = ((kt_) == T - 1);                                   \
        _Pragma("unroll")                                                      \
        for (int g = 0; g < 2; ++g) {                                          \
            f32x4 sg[4];                                                       \
            __builtin_amdgcn_s_setprio(1);                                     \
            _Pragma("unroll")                                                  \
            for (int nt = 0; nt < 4; ++nt) {                                   \
                sg[nt] = mfma16x16x32(kf[nt][0], aq[g][0],                     \
                                      f32x4{0.f, 0.f, 0.f, 0.f});              \
                sg[nt] = mfma16x16x32(kf[nt][1], aq[g][1], sg[nt]);            \
            }                                                                  \
            __builtin_amdgcn_s_setprio(0);                                     \
            if (lastt) {                                                       \
                const int qg = base + g * 16 + lr;                             \
                _Pragma("unroll")                                              \
                for (int nt = 0; nt < 4; ++nt) {                               \
                    bf16x4 pk;                                                 \
                    _Pragma("unroll")                                          \
                    for (int j = 0; j < 4; ++j) {                              \
                        float s = sg[nt][j];                                   \
                        s = (k0 + nt * 16 + quad * 4 + j > qg) ? -3.0e38f : s; \
                        pk[j] = (bf16)EXP2F(s);                                \
                    }                                                          \
                    *(bf16x4*)&Pb[(g * 16 + lr) * 72 + nt * 16 + quad * 4] = pk; \
                }                                                              \
            } else {                                                           \
                _Pragma("unroll")                                              \
                for (int nt = 0; nt < 4; ++nt) {                               \
                    bf16x4 pk;                                                 \
                    _Pragma("unroll")                                          \
                    for (int j = 0; j < 4; ++j) pk[j] = (bf16)EXP2F(sg[nt][j]); \
                    *(bf16x4*)&Pb[(g * 16 + lr) * 72 + nt * 16 + quad * 4] = pk; \
                }                                                              \
            }                                                                  \
        }                                                                      \
        __builtin_amdgcn_s_setprio(1);                                         \
        _Pragma("unroll")                                                      \
        for (int g = 0; g < 2; ++g)                                            \
            _Pragma("unroll")                                                  \
            for (int kk = 0; kk < 2; ++kk) {                                   \
                bf16x8 pa = *(const bf16x8*)&Pb[(g * 16 + lr) * 72 + kk * 32 + quad * 8]; \
                lacc[g] = mfma16x16x32(pa, ones, lacc[g]);                     \
                _Pragma("unroll")                                              \
                for (int nt = 0; nt < 4; ++nt)                                 \
                    o[g][nt] = mfma16x16x32(pa, vf[nt][kk], o[g][nt]);         \
            }                                                                  \
        __builtin_amdgcn_s_setprio(0);                                         \
    } while (0)

__global__ __launch_bounds__(128, 2) void attn(
    const bf16* __restrict__ q, const bf16* __restrict__ k,
    const bf16* __restrict__ vt, bf16* __restrict__ ctx)
{
    __shared__ bf16 Pl[2][2][32 * 72];   // [wave][buf][qrow*72+key]

    const int tid  = threadIdx.x;
    const int wave = tid >> 6;
    const int lane = tid & 63;
    const int quad = lane >> 4;
    const int lr   = lane & 15;

    const int bh = blockIdx.x;
    const int p  = blockIdx.y;           // 0..15

    const int b = bh >> 4;
    const int h = bh & 15;

    // Q,K in [B,S,D]: row = b*kS + s, col = h*64 + hd
    const bf16* qb_p = q  + (size_t)b * kS * kD + h * kHD;
    const bf16* kb_p = k  + (size_t)b * kS * kD + h * kHD;
    const bf16* vt_p = vt + (size_t)bh * kHD * kS; // [hd][s]

    bf16x8 ones;
#pragma unroll
    for (int i = 0; i < 8; ++i) ones[i] = (bf16)1.0f;

    // per-lane base element offsets
    const size_t koff = (size_t)lr * kD + quad * 8;    // + (kt*64+nt*16)*kD + kk*32
    const size_t voff = (size_t)lr * kS + quad * 8;    // + nt*16*2048 + kt*64 + kk*32
    bf16* Pw = &Pl[wave][0][0];

#pragma unroll 1
    for (int gi = 0; gi < 2; ++gi) {
        const int qb   = gi ? p : (31 - p);   // q-block 0..31 (heavy first)
        const int T    = qb + 1;              // k-tiles
        const int base = qb * 64 + wave * 32; // first q-row of this wave

        bf16x8 aq[2][2];
#pragma unroll
        for (int g = 0; g < 2; ++g)
#pragma unroll
            for (int kk = 0; kk < 2; ++kk)
                aq[g][kk] = *(const bf16x8*)&qb_p[(size_t)(base + g * 16 + lr) * kD + kk * 32 + quad * 8];

        f32x4 o[2][4];
        f32x4 lacc[2];
#pragma unroll
        for (int g = 0; g < 2; ++g) {
            lacc[g] = f32x4{0.f, 0.f, 0.f, 0.f};
#pragma unroll
            for (int nt = 0; nt < 4; ++nt) o[g][nt] = f32x4{0.f, 0.f, 0.f, 0.f};
        }

        bf16x8 kfA[4][2], kfB[4][2];
        LOADK(kfA, 0);
        int kt = 0;
        while (true) {
            {
                bf16x8 vf[4][2];
                LOADV(vf, kt);                       // V(t): ready by PV phase
                if (kt + 1 < T) LOADK(kfB, kt + 1);  // K(t+1): ready next tile
                COMPUTE(kfA, vf, kt);
            }
            if (++kt == T) break;
            {
                bf16x8 vf[4][2];
                LOADV(vf, kt);
                if (kt + 1 < T) LOADK(kfA, kt + 1);
                COMPUTE(kfB, vf, kt);
            }
            if (++kt == T) break;
        }

        // ctx [B,S,D] bf16, column h*64+hd
#pragma unroll
        for (int g = 0; g < 2; ++g) {
            float inv[4];
#pragma unroll
            for (int j = 0; j < 4; ++j) inv[j] = 1.0f / lacc[g][j];
#pragma unroll
            for (int nt = 0; nt < 4; ++nt) {
                int hd = nt * 16 + lr;
#pragma unroll
                for (int j = 0; j < 4; ++j) {
                    int qg = base + g * 16 + quad * 4 + j;
                    ctx[((size_t)(b * kS + qg)) * kD + h * kHD + hd] = (bf16)(o[g][nt][j] * inv[j]);
                }
            }
        }
    }
}

// ---------------------------------------------------------------------------
// out_gemm: out = ctx @ Wo + bo (fp32).  Same m97 structure.
// ---------------------------------------------------------------------------
__global__ __launch_bounds__(256) void out_gemm(
    const bf16* __restrict__ ctxb, const bf16* __restrict__ Wto,
    const float* __restrict__ bo, float* __restrict__ out)
{
    __shared__ bf16 As[128 * 64];
    __shared__ bf16 Bs[128 * 64];

    const int tid  = threadIdx.x;
    const int wave = tid >> 6;
    const int lane = tid & 63;
    const int quad = lane >> 4;
    const int lr   = lane & 15;
    const int wm   = wave >> 1, wn = wave & 1;

    const int m0 = blockIdx.x * 128;
    const int n0 = blockIdx.y * 128;

    const int sr = tid >> 3, sc = tid & 7;

    f32x4 acc[4][4];
#pragma unroll
    for (int i = 0; i < 4; ++i)
#pragma unroll
        for (int nt = 0; nt < 4; ++nt) acc[i][nt] = f32x4{0.f, 0.f, 0.f, 0.f};

    for (int k0 = 0; k0 < kD; k0 += 64) {
        __syncthreads();
#pragma unroll
        for (int p = 0; p < 4; ++p) {
            int r = p * 32 + sr;
            load_lds16(&ctxb[(size_t)(m0 + r) * kD + k0 + sc * 8],
                       &As[(p * 256 + wave * 64) * 8]);
            load_lds16(&Wto[(size_t)(n0 + r) * kD + k0 + sc * 8],
                       &Bs[(p * 256 + wave * 64) * 8]);
        }
        __syncthreads();
#pragma unroll
        for (int kk = 0; kk < 2; ++kk) {
            bf16x8 a[4], b[4];
#pragma unroll
            for (int i = 0; i < 4; ++i)
                a[i] = *(const bf16x8*)&As[(wm * 64 + i * 16 + lr) * 64 + kk * 32 + quad * 8];
#pragma unroll
            for (int nt = 0; nt < 4; ++nt)
                b[nt] = *(const bf16x8*)&Bs[(wn * 64 + nt * 16 + lr) * 64 + kk * 32 + quad * 8];
#pragma unroll
            for (int i = 0; i < 4; ++i)
#pragma unroll
                for (int nt = 0; nt < 4; ++nt)
                    acc[i][nt] = mfma16x16x32(a[i], b[nt], acc[i][nt]);
        }
    }

#pragma unroll
    for (int nt = 0; nt < 4; ++nt) {
        int n = n0 + wn * 64 + nt * 16 + lr;
        float bias = bo[n];
#pragma unroll
        for (int i = 0; i < 4; ++i)
#pragma unroll
            for (int j = 0; j < 4; ++j) {
                int m = m0 + wm * 64 + i * 16 + quad * 4 + j;
                out[(size_t)m * kD + n] = acc[i][nt][j] + bias;
            }
    }
}

// ---------------------------------------------------------------------------
extern "C" void kernel_launch(void* const* d_in, const int* in_sizes, int n_in,
                              void* d_out, int out_size, void* d_ws, size_t ws_size,
                              hipStream_t stream) {
    const float* x  = (const float*)d_in[0];
    const float* Wq = (const float*)d_in[1];
    const float* Wk = (const float*)d_in[2];
    const float* Wv = (const float*)d_in[3];
    const float* Wo = (const float*)d_in[4];
    const float* bo = (const float*)d_in[5];
    float* out = (float*)d_out;

    const size_t n_x   = (size_t)kB * kS * kD;       // 8,388,608
    const size_t n_w   = (size_t)4 * kD * kD;        // 4,194,304
    const size_t n_mat = (size_t)kB * kH * kS * kHD; // 8,388,608

    bf16* xb  = (bf16*)d_ws;        // 16 MB (reused as ctx after qkv_gemm)
    bf16* Wt  = xb + n_x;           // 8 MB
    bf16* Qm  = Wt + n_w;           // 16 MB [B,S,D]
    bf16* Km  = Qm + n_mat;         // 16 MB [B,S,D]
    bf16* Vt  = Km + n_mat;         // 16 MB [B,H,HD,S]
    bf16* ctx = xb;                 // reuse: x dead after qkv_gemm

    prep_x<<<dim3((int)(n_x / (256 * 8))), dim3(256), 0, stream>>>(x, xb);
    prep_w<<<dim3(16, 16, 4), dim3(256), 0, stream>>>(Wq, Wk, Wv, Wo, Wt);
    qkv_gemm<<<dim3(8192 / 128, 3072 / 128), dim3(256), 0, stream>>>(xb, Wt, Qm, Km, Vt);
    attn<<<dim3(kB * kH, 16), dim3(128), 0, stream>>>(Qm, Km, Vt, ctx);
    out_gemm<<<dim3(8192 / 128, 1024 / 128), dim3(256), 0, stream>>>(
        ctx, Wt + (size_t)3 * kD * kD, bo, out);
}

// Round 7
// 266.100 us; speedup vs baseline: 1.6468x; 1.2215x over previous
//
#include <hip/hip_runtime.h>
#include <math.h>
#include <stdint.h>

constexpr int kB = 4;
constexpr int kS = 2048;
constexpr int kD = 1024;
constexpr int kH = 16;
constexpr int kHD = 64;

typedef __bf16 bf16;
typedef __attribute__((ext_vector_type(4))) __bf16 bf16x4;
typedef __attribute__((ext_vector_type(8))) __bf16 bf16x8;
typedef __attribute__((ext_vector_type(4))) float f32x4;

__device__ __forceinline__ f32x4 mfma16x16x32(bf16x8 a, bf16x8 b, f32x4 c) {
    return __builtin_amdgcn_mfma_f32_16x16x32_bf16(a, b, c, 0, 0, 0);
}

#if __has_builtin(__builtin_amdgcn_exp2f)
#define EXP2F(x) __builtin_amdgcn_exp2f(x)
#else
#define EXP2F(x) exp2f(x)
#endif

// async 16B global->LDS. lds base must be wave-uniform (HW adds lane*16);
// the GLOBAL source address is per-lane -> arbitrary gather into linear LDS.
__device__ __forceinline__ void load_lds16(const bf16* g, bf16* lds) {
    __builtin_amdgcn_global_load_lds(
        (const __attribute__((address_space(1))) void*)g,
        (__attribute__((address_space(3))) void*)lds, 16, 0, 0);
}

// ---------------------------------------------------------------------------
// prep_x: fp32 -> bf16 convert of x (8192x1024).
// ---------------------------------------------------------------------------
__global__ __launch_bounds__(256) void prep_x(const float* __restrict__ x,
                                              bf16* __restrict__ xb) {
    size_t i = ((size_t)blockIdx.x * 256 + threadIdx.x) * 8;
    float4 f0 = *(const float4*)(x + i);
    float4 f1 = *(const float4*)(x + i + 4);
    bf16x8 v;
    v[0] = (bf16)f0.x; v[1] = (bf16)f0.y; v[2] = (bf16)f0.z; v[3] = (bf16)f0.w;
    v[4] = (bf16)f1.x; v[5] = (bf16)f1.y; v[6] = (bf16)f1.z; v[7] = (bf16)f1.w;
    *(bf16x8*)(xb + i) = v;
}

// ---------------------------------------------------------------------------
// prep_w: Wt[z*1024 + n][k] = W_z[k][n] * scale_z (bf16, transposed)
// z=0 Wq scaled by 0.125*log2(e) (exp2-domain softmax), 1=Wk, 2=Wv, 3=Wo.
// ---------------------------------------------------------------------------
__global__ __launch_bounds__(256) void prep_w(const float* __restrict__ Wq,
                                              const float* __restrict__ Wk,
                                              const float* __restrict__ Wv,
                                              const float* __restrict__ Wo,
                                              bf16* __restrict__ Wt) {
    __shared__ bf16 t[64 * 72];
    const int z = blockIdx.z;
    const float* W = (z == 0) ? Wq : (z == 1) ? Wk : (z == 2) ? Wv : Wo;
    const float scale = (z == 0) ? 0.18033688011112042f : 1.0f;
    const int k0 = blockIdx.x * 64, n0 = blockIdx.y * 64;
    const int tid = threadIdx.x;
    for (int p = 0; p < 16; ++p) {
        int idx = tid + p * 256;
        int r = idx >> 6, c = idx & 63;
        t[r * 72 + c] = (bf16)(W[(size_t)(k0 + r) * kD + n0 + c] * scale);
    }
    __syncthreads();
    for (int p = 0; p < 16; ++p) {
        int idx = tid + p * 256;
        int r = idx >> 6, c = idx & 63;
        Wt[(size_t)(z * 1024 + n0 + r) * kD + k0 + c] = t[c * 72 + r];
    }
}

// ---------------------------------------------------------------------------
// qkv_gemm: m97 structure. 128x128 tile, BK=64, unpadded LDS, staged via
// global_load_lds width=16.  4 waves 2x2, each 64x64.
// Q,K -> natural [B,S,D] layout (coalesced stores).  V -> [B,H,HD,S].
// ---------------------------------------------------------------------------
__global__ __launch_bounds__(256) void qkv_gemm(
    const bf16* __restrict__ xb, const bf16* __restrict__ Wt,
    bf16* __restrict__ qo, bf16* __restrict__ ko, bf16* __restrict__ vto)
{
    __shared__ bf16 As[128 * 64];
    __shared__ bf16 Bs[128 * 64];

    const int tid  = threadIdx.x;
    const int wave = tid >> 6;
    const int lane = tid & 63;
    const int quad = lane >> 4;
    const int lr   = lane & 15;
    const int wm   = wave >> 1, wn = wave & 1;

    const int m0 = blockIdx.x * 128;
    const int n0 = blockIdx.y * 128;

    const int sr = tid >> 3, sc = tid & 7;   // staging row/16B-block (per p: +32 rows)

    f32x4 acc[4][4];
#pragma unroll
    for (int i = 0; i < 4; ++i)
#pragma unroll
        for (int nt = 0; nt < 4; ++nt) acc[i][nt] = f32x4{0.f, 0.f, 0.f, 0.f};

    for (int k0 = 0; k0 < kD; k0 += 64) {
        __syncthreads();
#pragma unroll
        for (int p = 0; p < 4; ++p) {
            int r = p * 32 + sr;
            load_lds16(&xb[(size_t)(m0 + r) * kD + k0 + sc * 8],
                       &As[(p * 256 + wave * 64) * 8]);
            load_lds16(&Wt[(size_t)(n0 + r) * kD + k0 + sc * 8],
                       &Bs[(p * 256 + wave * 64) * 8]);
        }
        __syncthreads();
#pragma unroll
        for (int kk = 0; kk < 2; ++kk) {
            bf16x8 a[4], b[4];
#pragma unroll
            for (int i = 0; i < 4; ++i)
                a[i] = *(const bf16x8*)&As[(wm * 64 + i * 16 + lr) * 64 + kk * 32 + quad * 8];
#pragma unroll
            for (int nt = 0; nt < 4; ++nt)
                b[nt] = *(const bf16x8*)&Bs[(wn * 64 + nt * 16 + lr) * 64 + kk * 32 + quad * 8];
#pragma unroll
            for (int i = 0; i < 4; ++i)
#pragma unroll
                for (int nt = 0; nt < 4; ++nt)
                    acc[i][nt] = mfma16x16x32(a[i], b[nt], acc[i][nt]);
        }
    }

    const int w_idx = n0 >> 10;               // 0=Q,1=K,2=V (uniform per block)
    if (w_idx < 2) {
        bf16* dst = (w_idx == 0) ? qo : ko;   // [B,S,D] natural layout
#pragma unroll
        for (int i = 0; i < 4; ++i)
#pragma unroll
            for (int nt = 0; nt < 4; ++nt) {
                int n   = n0 + wn * 64 + nt * 16 + lr;
                int col = n & 1023;
#pragma unroll
                for (int j = 0; j < 4; ++j) {
                    int m = m0 + wm * 64 + i * 16 + quad * 4 + j;
                    dst[(size_t)m * kD + col] = (bf16)acc[i][nt][j];
                }
            }
    } else {
        // V transposed: [B,H,HD,S]; j walks s -> bf16x4 stores
#pragma unroll
        for (int i = 0; i < 4; ++i)
#pragma unroll
            for (int nt = 0; nt < 4; ++nt) {
                int n   = n0 + wn * 64 + nt * 16 + lr;
                int col = n & 1023, h = col >> 6, hd = col & 63;
                int mb  = m0 + wm * 64 + i * 16 + quad * 4;
                int b = mb >> 11, s = mb & 2047;
                bf16x4 pk;
#pragma unroll
                for (int j = 0; j < 4; ++j) pk[j] = (bf16)acc[i][nt][j];
                *(bf16x4*)&vto[((size_t)(b * kH + h) * kHD + hd) * kS + s] = pk;
            }
    }
}

// ---------------------------------------------------------------------------
// attn v10: kill the VMEM-request bottleneck.  v5/v9's register K/V loads
// issue 512 scattered 64B transactions per wave-tile, DUPLICATED by both
// waves (1024/block-tile) -> ~4k cy/tile-time of request processing per CU
// (the measured 9.4k-cy tile wall; MFMA needs only ~1k).  Now K and V tiles
// are gather-staged into LDS via global_load_lds with PER-LANE global source:
// 16 instrs x 8 coalesced 128B segments = 128 transactions per block-tile
// (8x fewer), shared by both waves.  Double-buffered; wave0 stages K, wave1
// stages V; one __syncthreads per tile (its implicit vmcnt drain is the wait
// -- loads get a full tile of compute to land).
// LDS frag reads use the XOR chunk-swizzle (pre-swizzled global source,
// linear LDS dest, m173 pattern): chunk = (kk*4+quad) ^ (lr&7) -> b128 reads
// at the conflict-free floor.  LDS 41KB -> 3 blocks/CU, so pairing is
// dropped: 2048 single-q-block jobs, heavy-first, LPT backfill.
// Unchanged: swapped QK^T, exp2-domain unnormalized softmax, P via per-wave
// LDS, register Q, causal mask on the diagonal tile only.
// ---------------------------------------------------------------------------
__global__ __launch_bounds__(128, 2) void attn(
    const bf16* __restrict__ q, const bf16* __restrict__ k,
    const bf16* __restrict__ vt, bf16* __restrict__ ctx)
{
    __shared__ bf16 Ks[2][64 * 64];     // [buf][s][hd]   (chunk-swizzled rows)
    __shared__ bf16 Vs[2][64 * 64];     // [buf][hd][s]   (chunk-swizzled rows)
    __shared__ bf16 Pl[2][32 * 72];     // [wave][qrow*72+key]

    const int tid  = threadIdx.x;
    const int wave = tid >> 6;
    const int lane = tid & 63;
    const int quad = lane >> 4;
    const int lr   = lane & 15;

    const int bh = blockIdx.x;
    const int qb = gridDim.y - 1 - blockIdx.y;   // heavy blocks dispatch first
    const int b  = bh >> 4;
    const int h  = bh & 15;

    // Q,K in [B,S,D]: row = b*kS + s, col = h*64 + hd
    const bf16* qb_p = q  + (size_t)b * kS * kD + h * kHD;
    const bf16* kb_p = k  + (size_t)b * kS * kD + h * kHD;
    const bf16* vt_p = vt + (size_t)bh * kHD * kS; // [hd][s]

    const int T    = qb + 1;              // k-tiles
    const int base = qb * 64 + wave * 32; // first q-row of this wave

    // gather-staging source pattern: instr i, lane l -> row i*8 + (l>>3),
    // 16B chunk (l&7) ^ ((l>>3)&7)  (XOR swizzle; LDS dest stays linear)
    const int grow   = lane >> 3;
    const int gchunk = ((lane & 7) ^ (grow & 7)) * 8;  // element offset

    bf16x8 ones;
#pragma unroll
    for (int i = 0; i < 8; ++i) ones[i] = (bf16)1.0f;

    bf16x8 aq[2][2];
#pragma unroll
    for (int g = 0; g < 2; ++g)
#pragma unroll
        for (int kk = 0; kk < 2; ++kk)
            aq[g][kk] = *(const bf16x8*)&qb_p[(size_t)(base + g * 16 + lr) * kD + kk * 32 + quad * 8];

    f32x4 o[2][4];
    f32x4 lacc[2];
#pragma unroll
    for (int g = 0; g < 2; ++g) {
        lacc[g] = f32x4{0.f, 0.f, 0.f, 0.f};
#pragma unroll
        for (int nt = 0; nt < 4; ++nt) o[g][nt] = f32x4{0.f, 0.f, 0.f, 0.f};
    }

    bf16* Pw = &Pl[wave][0];

    // prologue: stage tile 0 (wave0: K, wave1: V)
    if (wave == 0) {
#pragma unroll
        for (int i = 0; i < 8; ++i)
            load_lds16(kb_p + (size_t)(i * 8 + grow) * kD + gchunk, &Ks[0][i * 512]);
    } else {
#pragma unroll
        for (int i = 0; i < 8; ++i)
            load_lds16(vt_p + (size_t)(i * 8 + grow) * kS + gchunk, &Vs[0][i * 512]);
    }
    __syncthreads();

#pragma unroll 1
    for (int kt = 0; kt < T; ++kt) {
        const int k0  = kt * 64;
        const int buf = kt & 1;

        // issue next tile's staging into buf^1 (lands during this tile)
        if (kt + 1 < T) {
            const int nk0 = k0 + 64;
            if (wave == 0) {
#pragma unroll
                for (int i = 0; i < 8; ++i)
                    load_lds16(kb_p + (size_t)(nk0 + i * 8 + grow) * kD + gchunk,
                               &Ks[buf ^ 1][i * 512]);
            } else {
#pragma unroll
                for (int i = 0; i < 8; ++i)
                    load_lds16(vt_p + (size_t)(i * 8 + grow) * kS + nk0 + gchunk,
                               &Vs[buf ^ 1][i * 512]);
            }
        }

        // fragments from LDS (swizzled chunk index)
        bf16x8 kf[4][2], vf[4][2];
#pragma unroll
        for (int nt = 0; nt < 4; ++nt)
#pragma unroll
            for (int kk = 0; kk < 2; ++kk) {
                const int sw = ((kk * 4 + quad) ^ (lr & 7)) << 3;
                kf[nt][kk] = *(const bf16x8*)&Ks[buf][(nt * 16 + lr) * 64 + sw];
                vf[nt][kk] = *(const bf16x8*)&Vs[buf][(nt * 16 + lr) * 64 + sw];
            }

        const bool lastt = (kt == T - 1);
#pragma unroll
        for (int g = 0; g < 2; ++g) {
            // swapped QK^T: lane holds q-row = base+g*16+lr,
            // keys k0 + nt*16 + quad*4 + j (4 consecutive keys per reg)
            f32x4 sg[4];
            __builtin_amdgcn_s_setprio(1);
#pragma unroll
            for (int nt = 0; nt < 4; ++nt) {
                sg[nt] = mfma16x16x32(kf[nt][0], aq[g][0], f32x4{0.f, 0.f, 0.f, 0.f});
                sg[nt] = mfma16x16x32(kf[nt][1], aq[g][1], sg[nt]);
            }
            __builtin_amdgcn_s_setprio(0);
            if (lastt) {
                const int qg = base + g * 16 + lr;
#pragma unroll
                for (int nt = 0; nt < 4; ++nt) {
                    bf16x4 pk;
#pragma unroll
                    for (int j = 0; j < 4; ++j) {
                        float s = sg[nt][j];
                        s = (k0 + nt * 16 + quad * 4 + j > qg) ? -3.0e38f : s;
                        pk[j] = (bf16)EXP2F(s);
                    }
                    *(bf16x4*)&Pw[(g * 16 + lr) * 72 + nt * 16 + quad * 4] = pk;
                }
            } else {
#pragma unroll
                for (int nt = 0; nt < 4; ++nt) {
                    bf16x4 pk;
#pragma unroll
                    for (int j = 0; j < 4; ++j) pk[j] = (bf16)EXP2F(sg[nt][j]);
                    *(bf16x4*)&Pw[(g * 16 + lr) * 72 + nt * 16 + quad * 4] = pk;
                }
            }
        }

        // O += P @ V ; l += P @ ones   (P read back in A-operand layout)
        __builtin_amdgcn_s_setprio(1);
#pragma unroll
        for (int g = 0; g < 2; ++g)
#pragma unroll
            for (int kk = 0; kk < 2; ++kk) {
                bf16x8 pa = *(const bf16x8*)&Pw[(g * 16 + lr) * 72 + kk * 32 + quad * 8];
                lacc[g] = mfma16x16x32(pa, ones, lacc[g]);
#pragma unroll
                for (int nt = 0; nt < 4; ++nt)
                    o[g][nt] = mfma16x16x32(pa, vf[nt][kk], o[g][nt]);
            }
        __builtin_amdgcn_s_setprio(0);

        // barrier: (a) both waves done reading buf before stage(kt+2)
        // overwrites it next iteration; (b) implicit vmcnt/lgkm drain
        // guarantees stage(kt+1) landed before buf^1 is read.
        __syncthreads();
    }

    // ctx [B,S,D] bf16, column h*64+hd
#pragma unroll
    for (int g = 0; g < 2; ++g) {
        float inv[4];
#pragma unroll
        for (int j = 0; j < 4; ++j) inv[j] = 1.0f / lacc[g][j];
#pragma unroll
        for (int nt = 0; nt < 4; ++nt) {
            int hd = nt * 16 + lr;
#pragma unroll
            for (int j = 0; j < 4; ++j) {
                int qg = base + g * 16 + quad * 4 + j;
                ctx[((size_t)(b * kS + qg)) * kD + h * kHD + hd] = (bf16)(o[g][nt][j] * inv[j]);
            }
        }
    }
}

// ---------------------------------------------------------------------------
// out_gemm: out = ctx @ Wo + bo (fp32).  Same m97 structure.
// ---------------------------------------------------------------------------
__global__ __launch_bounds__(256) void out_gemm(
    const bf16* __restrict__ ctxb, const bf16* __restrict__ Wto,
    const float* __restrict__ bo, float* __restrict__ out)
{
    __shared__ bf16 As[128 * 64];
    __shared__ bf16 Bs[128 * 64];

    const int tid  = threadIdx.x;
    const int wave = tid >> 6;
    const int lane = tid & 63;
    const int quad = lane >> 4;
    const int lr   = lane & 15;
    const int wm   = wave >> 1, wn = wave & 1;

    const int m0 = blockIdx.x * 128;
    const int n0 = blockIdx.y * 128;

    const int sr = tid >> 3, sc = tid & 7;

    f32x4 acc[4][4];
#pragma unroll
    for (int i = 0; i < 4; ++i)
#pragma unroll
        for (int nt = 0; nt < 4; ++nt) acc[i][nt] = f32x4{0.f, 0.f, 0.f, 0.f};

    for (int k0 = 0; k0 < kD; k0 += 64) {
        __syncthreads();
#pragma unroll
        for (int p = 0; p < 4; ++p) {
            int r = p * 32 + sr;
            load_lds16(&ctxb[(size_t)(m0 + r) * kD + k0 + sc * 8],
                       &As[(p * 256 + wave * 64) * 8]);
            load_lds16(&Wto[(size_t)(n0 + r) * kD + k0 + sc * 8],
                       &Bs[(p * 256 + wave * 64) * 8]);
        }
        __syncthreads();
#pragma unroll
        for (int kk = 0; kk < 2; ++kk) {
            bf16x8 a[4], b[4];
#pragma unroll
            for (int i = 0; i < 4; ++i)
                a[i] = *(const bf16x8*)&As[(wm * 64 + i * 16 + lr) * 64 + kk * 32 + quad * 8];
#pragma unroll
            for (int nt = 0; nt < 4; ++nt)
                b[nt] = *(const bf16x8*)&Bs[(wn * 64 + nt * 16 + lr) * 64 + kk * 32 + quad * 8];
#pragma unroll
            for (int i = 0; i < 4; ++i)
#pragma unroll
                for (int nt = 0; nt < 4; ++nt)
                    acc[i][nt] = mfma16x16x32(a[i], b[nt], acc[i][nt]);
        }
    }

#pragma unroll
    for (int nt = 0; nt < 4; ++nt) {
        int n = n0 + wn * 64 + nt * 16 + lr;
        float bias = bo[n];
#pragma unroll
        for (int i = 0; i < 4; ++i)
#pragma unroll
            for (int j = 0; j < 4; ++j) {
                int m = m0 + wm * 64 + i * 16 + quad * 4 + j;
                out[(size_t)m * kD + n] = acc[i][nt][j] + bias;
            }
    }
}

// ---------------------------------------------------------------------------
extern "C" void kernel_launch(void* const* d_in, const int* in_sizes, int n_in,
                              void* d_out, int out_size, void* d_ws, size_t ws_size,
                              hipStream_t stream) {
    const float* x  = (const float*)d_in[0];
    const float* Wq = (const float*)d_in[1];
    const float* Wk = (const float*)d_in[2];
    const float* Wv = (const float*)d_in[3];
    const float* Wo = (const float*)d_in[4];
    const float* bo = (const float*)d_in[5];
    float* out = (float*)d_out;

    const size_t n_x   = (size_t)kB * kS * kD;       // 8,388,608
    const size_t n_w   = (size_t)4 * kD * kD;        // 4,194,304
    const size_t n_mat = (size_t)kB * kH * kS * kHD; // 8,388,608

    bf16* xb  = (bf16*)d_ws;        // 16 MB (reused as ctx after qkv_gemm)
    bf16* Wt  = xb + n_x;           // 8 MB
    bf16* Qm  = Wt + n_w;           // 16 MB [B,S,D]
    bf16* Km  = Qm + n_mat;         // 16 MB [B,S,D]
    bf16* Vt  = Km + n_mat;         // 16 MB [B,H,HD,S]
    bf16* ctx = xb;                 // reuse: x dead after qkv_gemm

    prep_x<<<dim3((int)(n_x / (256 * 8))), dim3(256), 0, stream>>>(x, xb);
    prep_w<<<dim3(16, 16, 4), dim3(256), 0, stream>>>(Wq, Wk, Wv, Wo, Wt);
    qkv_gemm<<<dim3(8192 / 128, 3072 / 128), dim3(256), 0, stream>>>(xb, Wt, Qm, Km, Vt);
    attn<<<dim3(kB * kH, 32), dim3(128), 0, stream>>>(Qm, Km, Vt, ctx);
    out_gemm<<<dim3(8192 / 128, 1024 / 128), dim3(256), 0, stream>>>(
        ctx, Wt + (size_t)3 * kD * kD, bo, out);
}

// Round 8
// 248.395 us; speedup vs baseline: 1.7641x; 1.0713x over previous
//
#include <hip/hip_runtime.h>
#include <math.h>
#include <stdint.h>

constexpr int kB = 4;
constexpr int kS = 2048;
constexpr int kD = 1024;
constexpr int kH = 16;
constexpr int kHD = 64;

typedef __bf16 bf16;
typedef __attribute__((ext_vector_type(4))) __bf16 bf16x4;
typedef __attribute__((ext_vector_type(8))) __bf16 bf16x8;
typedef __attribute__((ext_vector_type(4))) float f32x4;

__device__ __forceinline__ f32x4 mfma16x16x32(bf16x8 a, bf16x8 b, f32x4 c) {
    return __builtin_amdgcn_mfma_f32_16x16x32_bf16(a, b, c, 0, 0, 0);
}

#if __has_builtin(__builtin_amdgcn_exp2f)
#define EXP2F(x) __builtin_amdgcn_exp2f(x)
#else
#define EXP2F(x) exp2f(x)
#endif

// async 16B global->LDS. lds base must be wave-uniform (HW adds lane*16);
// the GLOBAL source address is per-lane -> arbitrary gather into linear LDS.
__device__ __forceinline__ void load_lds16(const bf16* g, bf16* lds) {
    __builtin_amdgcn_global_load_lds(
        (const __attribute__((address_space(1))) void*)g,
        (__attribute__((address_space(3))) void*)lds, 16, 0, 0);
}

// ---------------------------------------------------------------------------
// prep_x: fp32 -> bf16 convert of x (8192x1024).
// ---------------------------------------------------------------------------
__global__ __launch_bounds__(256) void prep_x(const float* __restrict__ x,
                                              bf16* __restrict__ xb) {
    size_t i = ((size_t)blockIdx.x * 256 + threadIdx.x) * 8;
    float4 f0 = *(const float4*)(x + i);
    float4 f1 = *(const float4*)(x + i + 4);
    bf16x8 v;
    v[0] = (bf16)f0.x; v[1] = (bf16)f0.y; v[2] = (bf16)f0.z; v[3] = (bf16)f0.w;
    v[4] = (bf16)f1.x; v[5] = (bf16)f1.y; v[6] = (bf16)f1.z; v[7] = (bf16)f1.w;
    *(bf16x8*)(xb + i) = v;
}

// ---------------------------------------------------------------------------
// prep_w: Wt[z*1024 + n][k] = W_z[k][n] * scale_z (bf16, transposed)
// z=0 Wq scaled by 0.125*log2(e) (exp2-domain softmax), 1=Wk, 2=Wv, 3=Wo.
// ---------------------------------------------------------------------------
__global__ __launch_bounds__(256) void prep_w(const float* __restrict__ Wq,
                                              const float* __restrict__ Wk,
                                              const float* __restrict__ Wv,
                                              const float* __restrict__ Wo,
                                              bf16* __restrict__ Wt) {
    __shared__ bf16 t[64 * 72];
    const int z = blockIdx.z;
    const float* W = (z == 0) ? Wq : (z == 1) ? Wk : (z == 2) ? Wv : Wo;
    const float scale = (z == 0) ? 0.18033688011112042f : 1.0f;
    const int k0 = blockIdx.x * 64, n0 = blockIdx.y * 64;
    const int tid = threadIdx.x;
    for (int p = 0; p < 16; ++p) {
        int idx = tid + p * 256;
        int r = idx >> 6, c = idx & 63;
        t[r * 72 + c] = (bf16)(W[(size_t)(k0 + r) * kD + n0 + c] * scale);
    }
    __syncthreads();
    for (int p = 0; p < 16; ++p) {
        int idx = tid + p * 256;
        int r = idx >> 6, c = idx & 63;
        Wt[(size_t)(z * 1024 + n0 + r) * kD + k0 + c] = t[c * 72 + r];
    }
}

// ---------------------------------------------------------------------------
// qkv_gemm v2: m97 structure with BK=32.  LDS 16KB -> 8 blocks/CU resident
// (was 32KB -> 5-capped, ~2 observed, Occupancy 19%).  R7 counters showed
// both-pipes-low + occupancy-low: the per-iter vmcnt(0) barrier drains had
// too few co-resident blocks to hide them (K=1024 -> only 16 iters at BK=64,
// each fully exposed).  BK=32 halves staged bytes/iter and raises residency
// to the wave cap; MFMA/iter/wave stays 16.
// 128x128 tile, 4 waves 2x2, each 64x64.
// Q,K -> natural [B,S,D] layout (coalesced stores).  V -> [B,H,HD,S].
// ---------------------------------------------------------------------------
__global__ __launch_bounds__(256) void qkv_gemm(
    const bf16* __restrict__ xb, const bf16* __restrict__ Wt,
    bf16* __restrict__ qo, bf16* __restrict__ ko, bf16* __restrict__ vto)
{
    __shared__ bf16 As[128 * 32];
    __shared__ bf16 Bs[128 * 32];

    const int tid  = threadIdx.x;
    const int wave = tid >> 6;
    const int lane = tid & 63;
    const int quad = lane >> 4;
    const int lr   = lane & 15;
    const int wm   = wave >> 1, wn = wave & 1;

    const int m0 = blockIdx.x * 128;
    const int n0 = blockIdx.y * 128;

    const int sr = tid >> 2, sc = tid & 3;   // staging row (0..63)/16B-chunk; +64 rows per p

    f32x4 acc[4][4];
#pragma unroll
    for (int i = 0; i < 4; ++i)
#pragma unroll
        for (int nt = 0; nt < 4; ++nt) acc[i][nt] = f32x4{0.f, 0.f, 0.f, 0.f};

    for (int k0 = 0; k0 < kD; k0 += 32) {
        __syncthreads();
#pragma unroll
        for (int p = 0; p < 2; ++p) {
            int r = p * 64 + sr;
            load_lds16(&xb[(size_t)(m0 + r) * kD + k0 + sc * 8],
                       &As[(p * 256 + wave * 64) * 8]);
            load_lds16(&Wt[(size_t)(n0 + r) * kD + k0 + sc * 8],
                       &Bs[(p * 256 + wave * 64) * 8]);
        }
        __syncthreads();
        bf16x8 a[4], b[4];
#pragma unroll
        for (int i = 0; i < 4; ++i)
            a[i] = *(const bf16x8*)&As[(wm * 64 + i * 16 + lr) * 32 + quad * 8];
#pragma unroll
        for (int nt = 0; nt < 4; ++nt)
            b[nt] = *(const bf16x8*)&Bs[(wn * 64 + nt * 16 + lr) * 32 + quad * 8];
#pragma unroll
        for (int i = 0; i < 4; ++i)
#pragma unroll
            for (int nt = 0; nt < 4; ++nt)
                acc[i][nt] = mfma16x16x32(a[i], b[nt], acc[i][nt]);
    }

    const int w_idx = n0 >> 10;               // 0=Q,1=K,2=V (uniform per block)
    if (w_idx < 2) {
        bf16* dst = (w_idx == 0) ? qo : ko;   // [B,S,D] natural layout
#pragma unroll
        for (int i = 0; i < 4; ++i)
#pragma unroll
            for (int nt = 0; nt < 4; ++nt) {
                int n   = n0 + wn * 64 + nt * 16 + lr;
                int col = n & 1023;
#pragma unroll
                for (int j = 0; j < 4; ++j) {
                    int m = m0 + wm * 64 + i * 16 + quad * 4 + j;
                    dst[(size_t)m * kD + col] = (bf16)acc[i][nt][j];
                }
            }
    } else {
        // V transposed: [B,H,HD,S]; j walks s -> bf16x4 stores
#pragma unroll
        for (int i = 0; i < 4; ++i)
#pragma unroll
            for (int nt = 0; nt < 4; ++nt) {
                int n   = n0 + wn * 64 + nt * 16 + lr;
                int col = n & 1023, h = col >> 6, hd = col & 63;
                int mb  = m0 + wm * 64 + i * 16 + quad * 4;
                int b = mb >> 11, s = mb & 2047;
                bf16x4 pk;
#pragma unroll
                for (int j = 0; j < 4; ++j) pk[j] = (bf16)acc[i][nt][j];
                *(bf16x4*)&vto[((size_t)(b * kH + h) * kHD + hd) * kS + s] = pk;
            }
    }
}

// ---------------------------------------------------------------------------
// attn v10 (UNCHANGED from R7; the VMEM-request fix, attn <89us).
// K/V gather-staged into LDS via global_load_lds with per-lane global source:
// 16 instrs x 8 coalesced 128B segments per block-tile (was 1024 scattered
// 64B transactions), shared by both waves.  Double-buffered; wave0 stages K,
// wave1 stages V; one __syncthreads per tile (implicit vmcnt drain = wait;
// stage(t+1) issued at top of tile t has the whole tile to land).
// XOR chunk-swizzle: pre-swizzled global source, linear LDS dest,
// read chunk = (kk*4+quad) ^ (lr&7).  2048 single-q-block jobs, heavy-first.
// Swapped QK^T, exp2-domain unnormalized softmax, P via per-wave LDS.
// ---------------------------------------------------------------------------
__global__ __launch_bounds__(128, 2) void attn(
    const bf16* __restrict__ q, const bf16* __restrict__ k,
    const bf16* __restrict__ vt, bf16* __restrict__ ctx)
{
    __shared__ bf16 Ks[2][64 * 64];     // [buf][s][hd]   (chunk-swizzled rows)
    __shared__ bf16 Vs[2][64 * 64];     // [buf][hd][s]   (chunk-swizzled rows)
    __shared__ bf16 Pl[2][32 * 72];     // [wave][qrow*72+key]

    const int tid  = threadIdx.x;
    const int wave = tid >> 6;
    const int lane = tid & 63;
    const int quad = lane >> 4;
    const int lr   = lane & 15;

    const int bh = blockIdx.x;
    const int qb = gridDim.y - 1 - blockIdx.y;   // heavy blocks dispatch first
    const int b  = bh >> 4;
    const int h  = bh & 15;

    // Q,K in [B,S,D]: row = b*kS + s, col = h*64 + hd
    const bf16* qb_p = q  + (size_t)b * kS * kD + h * kHD;
    const bf16* kb_p = k  + (size_t)b * kS * kD + h * kHD;
    const bf16* vt_p = vt + (size_t)bh * kHD * kS; // [hd][s]

    const int T    = qb + 1;              // k-tiles
    const int base = qb * 64 + wave * 32; // first q-row of this wave

    // gather-staging source pattern: instr i, lane l -> row i*8 + (l>>3),
    // 16B chunk (l&7) ^ ((l>>3)&7)  (XOR swizzle; LDS dest stays linear)
    const int grow   = lane >> 3;
    const int gchunk = ((lane & 7) ^ (grow & 7)) * 8;  // element offset

    bf16x8 ones;
#pragma unroll
    for (int i = 0; i < 8; ++i) ones[i] = (bf16)1.0f;

    bf16x8 aq[2][2];
#pragma unroll
    for (int g = 0; g < 2; ++g)
#pragma unroll
        for (int kk = 0; kk < 2; ++kk)
            aq[g][kk] = *(const bf16x8*)&qb_p[(size_t)(base + g * 16 + lr) * kD + kk * 32 + quad * 8];

    f32x4 o[2][4];
    f32x4 lacc[2];
#pragma unroll
    for (int g = 0; g < 2; ++g) {
        lacc[g] = f32x4{0.f, 0.f, 0.f, 0.f};
#pragma unroll
        for (int nt = 0; nt < 4; ++nt) o[g][nt] = f32x4{0.f, 0.f, 0.f, 0.f};
    }

    bf16* Pw = &Pl[wave][0];

    // prologue: stage tile 0 (wave0: K, wave1: V)
    if (wave == 0) {
#pragma unroll
        for (int i = 0; i < 8; ++i)
            load_lds16(kb_p + (size_t)(i * 8 + grow) * kD + gchunk, &Ks[0][i * 512]);
    } else {
#pragma unroll
        for (int i = 0; i < 8; ++i)
            load_lds16(vt_p + (size_t)(i * 8 + grow) * kS + gchunk, &Vs[0][i * 512]);
    }
    __syncthreads();

#pragma unroll 1
    for (int kt = 0; kt < T; ++kt) {
        const int k0  = kt * 64;
        const int buf = kt & 1;

        // issue next tile's staging into buf^1 (lands during this tile)
        if (kt + 1 < T) {
            const int nk0 = k0 + 64;
            if (wave == 0) {
#pragma unroll
                for (int i = 0; i < 8; ++i)
                    load_lds16(kb_p + (size_t)(nk0 + i * 8 + grow) * kD + gchunk,
                               &Ks[buf ^ 1][i * 512]);
            } else {
#pragma unroll
                for (int i = 0; i < 8; ++i)
                    load_lds16(vt_p + (size_t)(i * 8 + grow) * kS + nk0 + gchunk,
                               &Vs[buf ^ 1][i * 512]);
            }
        }

        // fragments from LDS (swizzled chunk index)
        bf16x8 kf[4][2], vf[4][2];
#pragma unroll
        for (int nt = 0; nt < 4; ++nt)
#pragma unroll
            for (int kk = 0; kk < 2; ++kk) {
                const int sw = ((kk * 4 + quad) ^ (lr & 7)) << 3;
                kf[nt][kk] = *(const bf16x8*)&Ks[buf][(nt * 16 + lr) * 64 + sw];
                vf[nt][kk] = *(const bf16x8*)&Vs[buf][(nt * 16 + lr) * 64 + sw];
            }

        const bool lastt = (kt == T - 1);
#pragma unroll
        for (int g = 0; g < 2; ++g) {
            // swapped QK^T: lane holds q-row = base+g*16+lr,
            // keys k0 + nt*16 + quad*4 + j (4 consecutive keys per reg)
            f32x4 sg[4];
            __builtin_amdgcn_s_setprio(1);
#pragma unroll
            for (int nt = 0; nt < 4; ++nt) {
                sg[nt] = mfma16x16x32(kf[nt][0], aq[g][0], f32x4{0.f, 0.f, 0.f, 0.f});
                sg[nt] = mfma16x16x32(kf[nt][1], aq[g][1], sg[nt]);
            }
            __builtin_amdgcn_s_setprio(0);
            if (lastt) {
                const int qg = base + g * 16 + lr;
#pragma unroll
                for (int nt = 0; nt < 4; ++nt) {
                    bf16x4 pk;
#pragma unroll
                    for (int j = 0; j < 4; ++j) {
                        float s = sg[nt][j];
                        s = (k0 + nt * 16 + quad * 4 + j > qg) ? -3.0e38f : s;
                        pk[j] = (bf16)EXP2F(s);
                    }
                    *(bf16x4*)&Pw[(g * 16 + lr) * 72 + nt * 16 + quad * 4] = pk;
                }
            } else {
#pragma unroll
                for (int nt = 0; nt < 4; ++nt) {
                    bf16x4 pk;
#pragma unroll
                    for (int j = 0; j < 4; ++j) pk[j] = (bf16)EXP2F(sg[nt][j]);
                    *(bf16x4*)&Pw[(g * 16 + lr) * 72 + nt * 16 + quad * 4] = pk;
                }
            }
        }

        // O += P @ V ; l += P @ ones   (P read back in A-operand layout)
        __builtin_amdgcn_s_setprio(1);
#pragma unroll
        for (int g = 0; g < 2; ++g)
#pragma unroll
            for (int kk = 0; kk < 2; ++kk) {
                bf16x8 pa = *(const bf16x8*)&Pw[(g * 16 + lr) * 72 + kk * 32 + quad * 8];
                lacc[g] = mfma16x16x32(pa, ones, lacc[g]);
#pragma unroll
                for (int nt = 0; nt < 4; ++nt)
                    o[g][nt] = mfma16x16x32(pa, vf[nt][kk], o[g][nt]);
            }
        __builtin_amdgcn_s_setprio(0);

        // barrier: (a) both waves done reading buf before stage(kt+2)
        // overwrites it next iteration; (b) implicit vmcnt/lgkm drain
        // guarantees stage(kt+1) landed before buf^1 is read.
        __syncthreads();
    }

    // ctx [B,S,D] bf16, column h*64+hd
#pragma unroll
    for (int g = 0; g < 2; ++g) {
        float inv[4];
#pragma unroll
        for (int j = 0; j < 4; ++j) inv[j] = 1.0f / lacc[g][j];
#pragma unroll
        for (int nt = 0; nt < 4; ++nt) {
            int hd = nt * 16 + lr;
#pragma unroll
            for (int j = 0; j < 4; ++j) {
                int qg = base + g * 16 + quad * 4 + j;
                ctx[((size_t)(b * kS + qg)) * kD + h * kHD + hd] = (bf16)(o[g][nt][j] * inv[j]);
            }
        }
    }
}

// ---------------------------------------------------------------------------
// out_gemm v2: out = ctx @ Wo + bo (fp32).  Same BK=32 conversion as qkv.
// ---------------------------------------------------------------------------
__global__ __launch_bounds__(256) void out_gemm(
    const bf16* __restrict__ ctxb, const bf16* __restrict__ Wto,
    const float* __restrict__ bo, float* __restrict__ out)
{
    __shared__ bf16 As[128 * 32];
    __shared__ bf16 Bs[128 * 32];

    const int tid  = threadIdx.x;
    const int wave = tid >> 6;
    const int lane = tid & 63;
    const int quad = lane >> 4;
    const int lr   = lane & 15;
    const int wm   = wave >> 1, wn = wave & 1;

    const int m0 = blockIdx.x * 128;
    const int n0 = blockIdx.y * 128;

    const int sr = tid >> 2, sc = tid & 3;

    f32x4 acc[4][4];
#pragma unroll
    for (int i = 0; i < 4; ++i)
#pragma unroll
        for (int nt = 0; nt < 4; ++nt) acc[i][nt] = f32x4{0.f, 0.f, 0.f, 0.f};

    for (int k0 = 0; k0 < kD; k0 += 32) {
        __syncthreads();
#pragma unroll
        for (int p = 0; p < 2; ++p) {
            int r = p * 64 + sr;
            load_lds16(&ctxb[(size_t)(m0 + r) * kD + k0 + sc * 8],
                       &As[(p * 256 + wave * 64) * 8]);
            load_lds16(&Wto[(size_t)(n0 + r) * kD + k0 + sc * 8],
                       &Bs[(p * 256 + wave * 64) * 8]);
        }
        __syncthreads();
        bf16x8 a[4], b[4];
#pragma unroll
        for (int i = 0; i < 4; ++i)
            a[i] = *(const bf16x8*)&As[(wm * 64 + i * 16 + lr) * 32 + quad * 8];
#pragma unroll
        for (int nt = 0; nt < 4; ++nt)
            b[nt] = *(const bf16x8*)&Bs[(wn * 64 + nt * 16 + lr) * 32 + quad * 8];
#pragma unroll
        for (int i = 0; i < 4; ++i)
#pragma unroll
            for (int nt = 0; nt < 4; ++nt)
                acc[i][nt] = mfma16x16x32(a[i], b[nt], acc[i][nt]);
    }

#pragma unroll
    for (int nt = 0; nt < 4; ++nt) {
        int n = n0 + wn * 64 + nt * 16 + lr;
        float bias = bo[n];
#pragma unroll
        for (int i = 0; i < 4; ++i)
#pragma unroll
            for (int j = 0; j < 4; ++j) {
                int m = m0 + wm * 64 + i * 16 + quad * 4 + j;
                out[(size_t)m * kD + n] = acc[i][nt][j] + bias;
            }
    }
}

// ---------------------------------------------------------------------------
extern "C" void kernel_launch(void* const* d_in, const int* in_sizes, int n_in,
                              void* d_out, int out_size, void* d_ws, size_t ws_size,
                              hipStream_t stream) {
    const float* x  = (const float*)d_in[0];
    const float* Wq = (const float*)d_in[1];
    const float* Wk = (const float*)d_in[2];
    const float* Wv = (const float*)d_in[3];
    const float* Wo = (const float*)d_in[4];
    const float* bo = (const float*)d_in[5];
    float* out = (float*)d_out;

    const size_t n_x   = (size_t)kB * kS * kD;       // 8,388,608
    const size_t n_w   = (size_t)4 * kD * kD;        // 4,194,304
    const size_t n_mat = (size_t)kB * kH * kS * kHD; // 8,388,608

    bf16* xb  = (bf16*)d_ws;        // 16 MB (reused as ctx after qkv_gemm)
    bf16* Wt  = xb + n_x;           // 8 MB
    bf16* Qm  = Wt + n_w;           // 16 MB [B,S,D]
    bf16* Km  = Qm + n_mat;         // 16 MB [B,S,D]
    bf16* Vt  = Km + n_mat;         // 16 MB [B,H,HD,S]
    bf16* ctx = xb;                 // reuse: x dead after qkv_gemm

    prep_x<<<dim3((int)(n_x / (256 * 8))), dim3(256), 0, stream>>>(x, xb);
    prep_w<<<dim3(16, 16, 4), dim3(256), 0, stream>>>(Wq, Wk, Wv, Wo, Wt);
    qkv_gemm<<<dim3(8192 / 128, 3072 / 128), dim3(256), 0, stream>>>(xb, Wt, Qm, Km, Vt);
    attn<<<dim3(kB * kH, 32), dim3(128), 0, stream>>>(Qm, Km, Vt, ctx);
    out_gemm<<<dim3(8192 / 128, 1024 / 128), dim3(256), 0, stream>>>(
        ctx, Wt + (size_t)3 * kD * kD, bo, out);
}

// Round 9
// 239.942 us; speedup vs baseline: 1.8263x; 1.0352x over previous
//
#include <hip/hip_runtime.h>
#include <math.h>
#include <stdint.h>

constexpr int kB = 4;
constexpr int kS = 2048;
constexpr int kD = 1024;
constexpr int kH = 16;
constexpr int kHD = 64;

typedef __bf16 bf16;
typedef __attribute__((ext_vector_type(4))) __bf16 bf16x4;
typedef __attribute__((ext_vector_type(8))) __bf16 bf16x8;
typedef __attribute__((ext_vector_type(4))) float f32x4;

__device__ __forceinline__ f32x4 mfma16x16x32(bf16x8 a, bf16x8 b, f32x4 c) {
    return __builtin_amdgcn_mfma_f32_16x16x32_bf16(a, b, c, 0, 0, 0);
}

#if __has_builtin(__builtin_amdgcn_exp2f)
#define EXP2F(x) __builtin_amdgcn_exp2f(x)
#else
#define EXP2F(x) exp2f(x)
#endif

// async 16B global->LDS. lds base must be wave-uniform (HW adds lane*16);
// the GLOBAL source address is per-lane -> arbitrary gather into linear LDS.
__device__ __forceinline__ void load_lds16(const bf16* g, bf16* lds) {
    __builtin_amdgcn_global_load_lds(
        (const __attribute__((address_space(1))) void*)g,
        (__attribute__((address_space(3))) void*)lds, 16, 0, 0);
}

// ---------------------------------------------------------------------------
// prep_x: fp32 -> bf16 convert of x (8192x1024).
// ---------------------------------------------------------------------------
__global__ __launch_bounds__(256) void prep_x(const float* __restrict__ x,
                                              bf16* __restrict__ xb) {
    size_t i = ((size_t)blockIdx.x * 256 + threadIdx.x) * 8;
    float4 f0 = *(const float4*)(x + i);
    float4 f1 = *(const float4*)(x + i + 4);
    bf16x8 v;
    v[0] = (bf16)f0.x; v[1] = (bf16)f0.y; v[2] = (bf16)f0.z; v[3] = (bf16)f0.w;
    v[4] = (bf16)f1.x; v[5] = (bf16)f1.y; v[6] = (bf16)f1.z; v[7] = (bf16)f1.w;
    *(bf16x8*)(xb + i) = v;
}

// ---------------------------------------------------------------------------
// prep_w: Wt[z*1024 + n][k] = W_z[k][n] * scale_z (bf16, transposed)
// z=0 Wq scaled by 0.125*log2(e) (exp2-domain softmax), 1=Wk, 2=Wv, 3=Wo.
// ---------------------------------------------------------------------------
__global__ __launch_bounds__(256) void prep_w(const float* __restrict__ Wq,
                                              const float* __restrict__ Wk,
                                              const float* __restrict__ Wv,
                                              const float* __restrict__ Wo,
                                              bf16* __restrict__ Wt) {
    __shared__ bf16 t[64 * 72];
    const int z = blockIdx.z;
    const float* W = (z == 0) ? Wq : (z == 1) ? Wk : (z == 2) ? Wv : Wo;
    const float scale = (z == 0) ? 0.18033688011112042f : 1.0f;
    const int k0 = blockIdx.x * 64, n0 = blockIdx.y * 64;
    const int tid = threadIdx.x;
    for (int p = 0; p < 16; ++p) {
        int idx = tid + p * 256;
        int r = idx >> 6, c = idx & 63;
        t[r * 72 + c] = (bf16)(W[(size_t)(k0 + r) * kD + n0 + c] * scale);
    }
    __syncthreads();
    for (int p = 0; p < 16; ++p) {
        int idx = tid + p * 256;
        int r = idx >> 6, c = idx & 63;
        Wt[(size_t)(z * 1024 + n0 + r) * kD + k0 + c] = t[c * 72 + r];
    }
}

// ---------------------------------------------------------------------------
// qkv_gemm v2 (unchanged from R8): m97 structure, BK=32, 16KB LDS -> high
// residency.  128x128 tile, 4 waves 2x2, each 64x64.
// Q,K -> natural [B,S,D] layout (coalesced stores).  V -> [B,H,HD,S].
// ---------------------------------------------------------------------------
__global__ __launch_bounds__(256) void qkv_gemm(
    const bf16* __restrict__ xb, const bf16* __restrict__ Wt,
    bf16* __restrict__ qo, bf16* __restrict__ ko, bf16* __restrict__ vto)
{
    __shared__ bf16 As[128 * 32];
    __shared__ bf16 Bs[128 * 32];

    const int tid  = threadIdx.x;
    const int wave = tid >> 6;
    const int lane = tid & 63;
    const int quad = lane >> 4;
    const int lr   = lane & 15;
    const int wm   = wave >> 1, wn = wave & 1;

    const int m0 = blockIdx.x * 128;
    const int n0 = blockIdx.y * 128;

    const int sr = tid >> 2, sc = tid & 3;   // staging row (0..63)/16B-chunk; +64 rows per p

    f32x4 acc[4][4];
#pragma unroll
    for (int i = 0; i < 4; ++i)
#pragma unroll
        for (int nt = 0; nt < 4; ++nt) acc[i][nt] = f32x4{0.f, 0.f, 0.f, 0.f};

    for (int k0 = 0; k0 < kD; k0 += 32) {
        __syncthreads();
#pragma unroll
        for (int p = 0; p < 2; ++p) {
            int r = p * 64 + sr;
            load_lds16(&xb[(size_t)(m0 + r) * kD + k0 + sc * 8],
                       &As[(p * 256 + wave * 64) * 8]);
            load_lds16(&Wt[(size_t)(n0 + r) * kD + k0 + sc * 8],
                       &Bs[(p * 256 + wave * 64) * 8]);
        }
        __syncthreads();
        bf16x8 a[4], b[4];
#pragma unroll
        for (int i = 0; i < 4; ++i)
            a[i] = *(const bf16x8*)&As[(wm * 64 + i * 16 + lr) * 32 + quad * 8];
#pragma unroll
        for (int nt = 0; nt < 4; ++nt)
            b[nt] = *(const bf16x8*)&Bs[(wn * 64 + nt * 16 + lr) * 32 + quad * 8];
#pragma unroll
        for (int i = 0; i < 4; ++i)
#pragma unroll
            for (int nt = 0; nt < 4; ++nt)
                acc[i][nt] = mfma16x16x32(a[i], b[nt], acc[i][nt]);
    }

    const int w_idx = n0 >> 10;               // 0=Q,1=K,2=V (uniform per block)
    if (w_idx < 2) {
        bf16* dst = (w_idx == 0) ? qo : ko;   // [B,S,D] natural layout
#pragma unroll
        for (int i = 0; i < 4; ++i)
#pragma unroll
            for (int nt = 0; nt < 4; ++nt) {
                int n   = n0 + wn * 64 + nt * 16 + lr;
                int col = n & 1023;
#pragma unroll
                for (int j = 0; j < 4; ++j) {
                    int m = m0 + wm * 64 + i * 16 + quad * 4 + j;
                    dst[(size_t)m * kD + col] = (bf16)acc[i][nt][j];
                }
            }
    } else {
        // V transposed: [B,H,HD,S]; j walks s -> bf16x4 stores
#pragma unroll
        for (int i = 0; i < 4; ++i)
#pragma unroll
            for (int nt = 0; nt < 4; ++nt) {
                int n   = n0 + wn * 64 + nt * 16 + lr;
                int col = n & 1023, h = col >> 6, hd = col & 63;
                int mb  = m0 + wm * 64 + i * 16 + quad * 4;
                int b = mb >> 11, s = mb & 2047;
                bf16x4 pk;
#pragma unroll
                for (int j = 0; j < 4; ++j) pk[j] = (bf16)acc[i][nt][j];
                *(bf16x4*)&vto[((size_t)(b * kH + h) * kHD + hd) * kS + s] = pk;
            }
    }
}

// ---------------------------------------------------------------------------
// attn v11: occupancy fix on the LDS-staged structure.  R8 counters: attn
// 72.7us, Occupancy 14% (41KB LDS -> 3 blocks/CU x 2 waves = 6 waves/CU max,
// ~1.1/SIMD) -- each per-tile __syncthreads vmcnt-drain had no other wave to
// run under it.  Unlike R3's register-load structure, staging here is
// PER-BLOCK (16 global_load_lds instrs shared by all waves), so adding waves
// costs zero extra VMEM transactions: 4 waves x 16 q-rows over the same
// 64-row q-block.  Same traffic, same total MFMA, 12 waves/CU (3 blk x 4).
// Wave0 stages K, wave1 stages V, double-buffered, one barrier per tile.
// XOR chunk-swizzle (pre-swizzled global source, linear LDS dest,
// read chunk = (kk*4+quad)^(lr&7)).  2048 single-q-block jobs, heavy-first.
// Swapped QK^T, exp2-domain unnormalized softmax, P via per-wave LDS.
// ---------------------------------------------------------------------------
__global__ __launch_bounds__(256, 3) void attn(
    const bf16* __restrict__ q, const bf16* __restrict__ k,
    const bf16* __restrict__ vt, bf16* __restrict__ ctx)
{
    __shared__ bf16 Ks[2][64 * 64];     // [buf][s][hd]   (chunk-swizzled rows)
    __shared__ bf16 Vs[2][64 * 64];     // [buf][hd][s]   (chunk-swizzled rows)
    __shared__ bf16 Pl[4][16 * 72];     // [wave][qrow*72+key]

    const int tid  = threadIdx.x;
    const int wave = tid >> 6;
    const int lane = tid & 63;
    const int quad = lane >> 4;
    const int lr   = lane & 15;

    const int bh = blockIdx.x;
    const int qb = gridDim.y - 1 - blockIdx.y;   // heavy blocks dispatch first
    const int b  = bh >> 4;
    const int h  = bh & 15;

    // Q,K in [B,S,D]: row = b*kS + s, col = h*64 + hd
    const bf16* qb_p = q  + (size_t)b * kS * kD + h * kHD;
    const bf16* kb_p = k  + (size_t)b * kS * kD + h * kHD;
    const bf16* vt_p = vt + (size_t)bh * kHD * kS; // [hd][s]

    const int T    = qb + 1;              // k-tiles
    const int base = qb * 64 + wave * 16; // first q-row of this wave

    // gather-staging source pattern: instr i, lane l -> row i*8 + (l>>3),
    // 16B chunk (l&7) ^ ((l>>3)&7)  (XOR swizzle; LDS dest stays linear)
    const int grow   = lane >> 3;
    const int gchunk = ((lane & 7) ^ (grow & 7)) * 8;  // element offset

    bf16x8 ones;
#pragma unroll
    for (int i = 0; i < 8; ++i) ones[i] = (bf16)1.0f;

    bf16x8 aq[2];
#pragma unroll
    for (int kk = 0; kk < 2; ++kk)
        aq[kk] = *(const bf16x8*)&qb_p[(size_t)(base + lr) * kD + kk * 32 + quad * 8];

    f32x4 o[4];
    f32x4 lacc = f32x4{0.f, 0.f, 0.f, 0.f};
#pragma unroll
    for (int nt = 0; nt < 4; ++nt) o[nt] = f32x4{0.f, 0.f, 0.f, 0.f};

    bf16* Pw = &Pl[wave][0];

    // prologue: stage tile 0 (wave0: K, wave1: V; waves 2,3 idle here)
    if (wave == 0) {
#pragma unroll
        for (int i = 0; i < 8; ++i)
            load_lds16(kb_p + (size_t)(i * 8 + grow) * kD + gchunk, &Ks[0][i * 512]);
    } else if (wave == 1) {
#pragma unroll
        for (int i = 0; i < 8; ++i)
            load_lds16(vt_p + (size_t)(i * 8 + grow) * kS + gchunk, &Vs[0][i * 512]);
    }
    __syncthreads();

#pragma unroll 1
    for (int kt = 0; kt < T; ++kt) {
        const int k0  = kt * 64;
        const int buf = kt & 1;

        // issue next tile's staging into buf^1 (lands during this tile)
        if (kt + 1 < T) {
            const int nk0 = k0 + 64;
            if (wave == 0) {
#pragma unroll
                for (int i = 0; i < 8; ++i)
                    load_lds16(kb_p + (size_t)(nk0 + i * 8 + grow) * kD + gchunk,
                               &Ks[buf ^ 1][i * 512]);
            } else if (wave == 1) {
#pragma unroll
                for (int i = 0; i < 8; ++i)
                    load_lds16(vt_p + (size_t)(i * 8 + grow) * kS + nk0 + gchunk,
                               &Vs[buf ^ 1][i * 512]);
            }
        }

        // fragments from LDS (swizzled chunk index)
        bf16x8 kf[4][2], vf[4][2];
#pragma unroll
        for (int nt = 0; nt < 4; ++nt)
#pragma unroll
            for (int kk = 0; kk < 2; ++kk) {
                const int sw = ((kk * 4 + quad) ^ (lr & 7)) << 3;
                kf[nt][kk] = *(const bf16x8*)&Ks[buf][(nt * 16 + lr) * 64 + sw];
                vf[nt][kk] = *(const bf16x8*)&Vs[buf][(nt * 16 + lr) * 64 + sw];
            }

        // swapped QK^T: lane holds q-row = base+lr,
        // keys k0 + nt*16 + quad*4 + j (4 consecutive keys per reg)
        f32x4 sg[4];
        __builtin_amdgcn_s_setprio(1);
#pragma unroll
        for (int nt = 0; nt < 4; ++nt) {
            sg[nt] = mfma16x16x32(kf[nt][0], aq[0], f32x4{0.f, 0.f, 0.f, 0.f});
            sg[nt] = mfma16x16x32(kf[nt][1], aq[1], sg[nt]);
        }
        __builtin_amdgcn_s_setprio(0);

        if (kt == T - 1) {
            const int qg = base + lr;
#pragma unroll
            for (int nt = 0; nt < 4; ++nt) {
                bf16x4 pk;
#pragma unroll
                for (int j = 0; j < 4; ++j) {
                    float s = sg[nt][j];
                    s = (k0 + nt * 16 + quad * 4 + j > qg) ? -3.0e38f : s;
                    pk[j] = (bf16)EXP2F(s);
                }
                *(bf16x4*)&Pw[lr * 72 + nt * 16 + quad * 4] = pk;
            }
        } else {
#pragma unroll
            for (int nt = 0; nt < 4; ++nt) {
                bf16x4 pk;
#pragma unroll
                for (int j = 0; j < 4; ++j) pk[j] = (bf16)EXP2F(sg[nt][j]);
                *(bf16x4*)&Pw[lr * 72 + nt * 16 + quad * 4] = pk;
            }
        }

        // O += P @ V ; l += P @ ones   (P read back in A-operand layout)
        __builtin_amdgcn_s_setprio(1);
#pragma unroll
        for (int kk = 0; kk < 2; ++kk) {
            bf16x8 pa = *(const bf16x8*)&Pw[lr * 72 + kk * 32 + quad * 8];
            lacc = mfma16x16x32(pa, ones, lacc);
#pragma unroll
            for (int nt = 0; nt < 4; ++nt)
                o[nt] = mfma16x16x32(pa, vf[nt][kk], o[nt]);
        }
        __builtin_amdgcn_s_setprio(0);

        // barrier: (a) all waves done reading buf before stage(kt+2)
        // overwrites it; (b) implicit vmcnt drain guarantees stage(kt+1)
        // landed before buf^1 is read.
        __syncthreads();
    }

    // ctx [B,S,D] bf16, column h*64+hd; rows base + quad*4 + j
    float inv[4];
#pragma unroll
    for (int j = 0; j < 4; ++j) inv[j] = 1.0f / lacc[j];
#pragma unroll
    for (int nt = 0; nt < 4; ++nt) {
        int hd = nt * 16 + lr;
#pragma unroll
        for (int j = 0; j < 4; ++j) {
            int qg = base + quad * 4 + j;
            ctx[((size_t)(b * kS + qg)) * kD + h * kHD + hd] = (bf16)(o[nt][j] * inv[j]);
        }
    }
}

// ---------------------------------------------------------------------------
// out_gemm v2 (unchanged from R8): out = ctx @ Wo + bo (fp32), BK=32.
// ---------------------------------------------------------------------------
__global__ __launch_bounds__(256) void out_gemm(
    const bf16* __restrict__ ctxb, const bf16* __restrict__ Wto,
    const float* __restrict__ bo, float* __restrict__ out)
{
    __shared__ bf16 As[128 * 32];
    __shared__ bf16 Bs[128 * 32];

    const int tid  = threadIdx.x;
    const int wave = tid >> 6;
    const int lane = tid & 63;
    const int quad = lane >> 4;
    const int lr   = lane & 15;
    const int wm   = wave >> 1, wn = wave & 1;

    const int m0 = blockIdx.x * 128;
    const int n0 = blockIdx.y * 128;

    const int sr = tid >> 2, sc = tid & 3;

    f32x4 acc[4][4];
#pragma unroll
    for (int i = 0; i < 4; ++i)
#pragma unroll
        for (int nt = 0; nt < 4; ++nt) acc[i][nt] = f32x4{0.f, 0.f, 0.f, 0.f};

    for (int k0 = 0; k0 < kD; k0 += 32) {
        __syncthreads();
#pragma unroll
        for (int p = 0; p < 2; ++p) {
            int r = p * 64 + sr;
            load_lds16(&ctxb[(size_t)(m0 + r) * kD + k0 + sc * 8],
                       &As[(p * 256 + wave * 64) * 8]);
            load_lds16(&Wto[(size_t)(n0 + r) * kD + k0 + sc * 8],
                       &Bs[(p * 256 + wave * 64) * 8]);
        }
        __syncthreads();
        bf16x8 a[4], b[4];
#pragma unroll
        for (int i = 0; i < 4; ++i)
            a[i] = *(const bf16x8*)&As[(wm * 64 + i * 16 + lr) * 32 + quad * 8];
#pragma unroll
        for (int nt = 0; nt < 4; ++nt)
            b[nt] = *(const bf16x8*)&Bs[(wn * 64 + nt * 16 + lr) * 32 + quad * 8];
#pragma unroll
        for (int i = 0; i < 4; ++i)
#pragma unroll
            for (int nt = 0; nt < 4; ++nt)
                acc[i][nt] = mfma16x16x32(a[i], b[nt], acc[i][nt]);
    }

#pragma unroll
    for (int nt = 0; nt < 4; ++nt) {
        int n = n0 + wn * 64 + nt * 16 + lr;
        float bias = bo[n];
#pragma unroll
        for (int i = 0; i < 4; ++i)
#pragma unroll
            for (int j = 0; j < 4; ++j) {
                int m = m0 + wm * 64 + i * 16 + quad * 4 + j;
                out[(size_t)m * kD + n] = acc[i][nt][j] + bias;
            }
    }
}

// ---------------------------------------------------------------------------
extern "C" void kernel_launch(void* const* d_in, const int* in_sizes, int n_in,
                              void* d_out, int out_size, void* d_ws, size_t ws_size,
                              hipStream_t stream) {
    const float* x  = (const float*)d_in[0];
    const float* Wq = (const float*)d_in[1];
    const float* Wk = (const float*)d_in[2];
    const float* Wv = (const float*)d_in[3];
    const float* Wo = (const float*)d_in[4];
    const float* bo = (const float*)d_in[5];
    float* out = (float*)d_out;

    const size_t n_x   = (size_t)kB * kS * kD;       // 8,388,608
    const size_t n_w   = (size_t)4 * kD * kD;        // 4,194,304
    const size_t n_mat = (size_t)kB * kH * kS * kHD; // 8,388,608

    bf16* xb  = (bf16*)d_ws;        // 16 MB (reused as ctx after qkv_gemm)
    bf16* Wt  = xb + n_x;           // 8 MB
    bf16* Qm  = Wt + n_w;           // 16 MB [B,S,D]
    bf16* Km  = Qm + n_mat;         // 16 MB [B,S,D]
    bf16* Vt  = Km + n_mat;         // 16 MB [B,H,HD,S]
    bf16* ctx = xb;                 // reuse: x dead after qkv_gemm

    prep_x<<<dim3((int)(n_x / (256 * 8))), dim3(256), 0, stream>>>(x, xb);
    prep_w<<<dim3(16, 16, 4), dim3(256), 0, stream>>>(Wq, Wk, Wv, Wo, Wt);
    qkv_gemm<<<dim3(8192 / 128, 3072 / 128), dim3(256), 0, stream>>>(xb, Wt, Qm, Km, Vt);
    attn<<<dim3(kB * kH, 32), dim3(256), 0, stream>>>(Qm, Km, Vt, ctx);
    out_gemm<<<dim3(8192 / 128, 1024 / 128), dim3(256), 0, stream>>>(
        ctx, Wt + (size_t)3 * kD * kD, bo, out);
}